// Round 1
// baseline (546.478 us; speedup 1.0000x reference)
//
#include <hip/hip_runtime.h>

#define DECAY 0.99f
#define OMD   0.01f   // 1 - DECAY
#define EPSV  1e-5f

constexpr int N_PTS   = 32768;  // B*T = 64*512
constexpr int D_DIM   = 256;
constexpr int C_CODES = 1024;

// workspace layout (floats)
constexpr int WS_COUNTS = 0;                          // [1024]
constexpr int WS_ESUM   = C_CODES;                    // [1024*256]
constexpr int WS_ENORM  = WS_ESUM + C_CODES * D_DIM;  // [1024]
constexpr int WS_DENOM  = WS_ENORM + C_CODES;         // [1024]

// ---------------------------------------------------------------------------
// enorm[c] = sum_d embed[c,d]^2.  One wave per code.
__global__ __launch_bounds__(256) void vq_enorm(const float* __restrict__ E,
                                                float* __restrict__ enorm) {
    int c    = blockIdx.x * 4 + (threadIdx.x >> 6);
    int lane = threadIdx.x & 63;
    const float4* E4 = reinterpret_cast<const float4*>(E);
    float4 v = E4[c * (D_DIM / 4) + lane];
    float s  = v.x * v.x + v.y * v.y + v.z * v.z + v.w * v.w;
#pragma unroll
    for (int off = 32; off > 0; off >>= 1) s += __shfl_down(s, off, 64);
    if (lane == 0) enorm[c] = s;
}

// ---------------------------------------------------------------------------
// Main: per 64-row block, tiled fp32 "GEMM" vs all 1024 codes with running
// row-argmax; epilogue does gather (quantize), histogram, and x scatter-add.
__global__ __launch_bounds__(256) void vq_main(
    const float* __restrict__ X, const float* __restrict__ E,
    const float* __restrict__ enorm,
    float* __restrict__ quant, float* __restrict__ indout,
    float* __restrict__ counts, float* __restrict__ esum) {
    constexpr int BN = 64, BC = 64, BK = 32, PADR = 68;
    __shared__ float As[BK * PADR];      // [k][row], padded
    __shared__ float Bs[BK * PADR];      // [k][code]
    __shared__ float redv[BN * 16];
    __shared__ int   redi[BN * 16];
    __shared__ int   rowsel[BN];

    const int tid = threadIdx.x;
    const int n0  = blockIdx.x * BN;
    const int tr  = tid >> 4;   // 0..15  (4 rows each)
    const int tc  = tid & 15;   // 0..15  (4 cols each)
    const int sr  = tid >> 2;   // staging row 0..63
    const int sk  = tid & 3;    // staging float4-in-chunk 0..3

    const float4* X4 = reinterpret_cast<const float4*>(X);
    const float4* E4 = reinterpret_cast<const float4*>(E);

    float best[4];
    int   bidx[4];
#pragma unroll
    for (int i = 0; i < 4; i++) { best[i] = -3.4e38f; bidx[i] = 0; }

    for (int c0 = 0; c0 < C_CODES; c0 += BC) {
        float acc[4][4];
#pragma unroll
        for (int i = 0; i < 4; i++)
#pragma unroll
            for (int j = 0; j < 4; j++) acc[i][j] = 0.0f;

        for (int k0 = 0; k0 < D_DIM; k0 += BK) {
            __syncthreads();
#pragma unroll
            for (int it = 0; it < 2; ++it) {
                int   k4 = sk + 4 * it;  // 0..7 (float4 within 32-float chunk)
                float4 av = X4[(n0 + sr) * (D_DIM / 4) + (k0 >> 2) + k4];
                float4 bv = E4[(c0 + sr) * (D_DIM / 4) + (k0 >> 2) + k4];
                int kk = k4 * 4;
                As[(kk + 0) * PADR + sr] = av.x;
                As[(kk + 1) * PADR + sr] = av.y;
                As[(kk + 2) * PADR + sr] = av.z;
                As[(kk + 3) * PADR + sr] = av.w;
                Bs[(kk + 0) * PADR + sr] = bv.x;
                Bs[(kk + 1) * PADR + sr] = bv.y;
                Bs[(kk + 2) * PADR + sr] = bv.z;
                Bs[(kk + 3) * PADR + sr] = bv.w;
            }
            __syncthreads();
#pragma unroll
            for (int k = 0; k < BK; ++k) {
                float4 a = *reinterpret_cast<const float4*>(&As[k * PADR + 4 * tr]);
                float4 b = *reinterpret_cast<const float4*>(&Bs[k * PADR + 4 * tc]);
                acc[0][0] += a.x * b.x; acc[0][1] += a.x * b.y;
                acc[0][2] += a.x * b.z; acc[0][3] += a.x * b.w;
                acc[1][0] += a.y * b.x; acc[1][1] += a.y * b.y;
                acc[1][2] += a.y * b.z; acc[1][3] += a.y * b.w;
                acc[2][0] += a.z * b.x; acc[2][1] += a.z * b.y;
                acc[2][2] += a.z * b.z; acc[2][3] += a.z * b.w;
                acc[3][0] += a.w * b.x; acc[3][1] += a.w * b.y;
                acc[3][2] += a.w * b.z; acc[3][3] += a.w * b.w;
            }
        }
        float4 en = *reinterpret_cast<const float4*>(&enorm[c0 + 4 * tc]);
        float enj[4] = {en.x, en.y, en.z, en.w};
#pragma unroll
        for (int i = 0; i < 4; i++)
#pragma unroll
            for (int j = 0; j < 4; j++) {
                float v = 2.0f * acc[i][j] - enj[j];
                int   c = c0 + 4 * tc + j;
                if (v > best[i]) { best[i] = v; bidx[i] = c; }  // strict > keeps first max
            }
    }

    __syncthreads();
#pragma unroll
    for (int i = 0; i < 4; i++) {
        redv[(4 * tr + i) * 16 + tc] = best[i];
        redi[(4 * tr + i) * 16 + tc] = bidx[i];
    }
    __syncthreads();
    if (tid < BN) {
        float bv = redv[tid * 16];
        int   bi = redi[tid * 16];
        for (int t = 1; t < 16; t++) {
            float v  = redv[tid * 16 + t];
            int   id = redi[tid * 16 + t];
            if (v > bv || (v == bv && id < bi)) { bv = v; bi = id; }
        }
        rowsel[tid] = bi;
        indout[n0 + tid] = (float)bi;
        unsafeAtomicAdd(&counts[bi], 1.0f);
    }
    __syncthreads();

    float4*   Q4   = reinterpret_cast<float4*>(quant);
    const int lane = tid & 63;
#pragma unroll
    for (int it = 0; it < 16; ++it) {
        int r   = (tid >> 6) + 4 * it;
        int idx = rowsel[r];
        float4 ev = E4[idx * (D_DIM / 4) + lane];
        Q4[(n0 + r) * (D_DIM / 4) + lane] = ev;
        float4 xv = X4[(n0 + r) * (D_DIM / 4) + lane];
        float* dst = &esum[idx * D_DIM + lane * 4];
        unsafeAtomicAdd(dst + 0, xv.x);
        unsafeAtomicAdd(dst + 1, xv.y);
        unsafeAtomicAdd(dst + 2, xv.z);
        unsafeAtomicAdd(dst + 3, xv.w);
    }
}

// ---------------------------------------------------------------------------
// cs_new + its sum + smoothed denominator
__global__ __launch_bounds__(1024) void vq_fin1(const float* __restrict__ cs_in,
                                                const float* __restrict__ counts,
                                                float* __restrict__ cs_out,
                                                float* __restrict__ denom) {
    __shared__ float red[1024];
    int   c  = threadIdx.x;
    float cs = DECAY * cs_in[c] + OMD * counts[c];
    cs_out[c] = cs;
    red[c]    = cs;
    __syncthreads();
    for (int s = 512; s > 0; s >>= 1) {
        if (c < s) red[c] += red[c + s];
        __syncthreads();
    }
    float ntot = red[0];
    denom[c] = (cs + EPSV) / (ntot + (float)C_CODES * EPSV) * ntot;
}

// embed_norm = (0.99*embed_avg + 0.01*embed_sum) / denom[c]
__global__ __launch_bounds__(256) void vq_fin2(const float* __restrict__ ea,
                                               const float* __restrict__ esum,
                                               const float* __restrict__ denom,
                                               float* __restrict__ out) {
    int i = blockIdx.x * 256 + threadIdx.x;  // float4 index over C*D/4
    const float4* ea4 = reinterpret_cast<const float4*>(ea);
    const float4* es4 = reinterpret_cast<const float4*>(esum);
    int    c = i >> 6;  // D/4 = 64 float4 per code
    float4 a = ea4[i];
    float4 s = es4[i];
    float  d = denom[c];
    float4 o;
    o.x = (DECAY * a.x + OMD * s.x) / d;
    o.y = (DECAY * a.y + OMD * s.y) / d;
    o.z = (DECAY * a.z + OMD * s.z) / d;
    o.w = (DECAY * a.w + OMD * s.w) / d;
    reinterpret_cast<float4*>(out)[i] = o;
}

// ---------------------------------------------------------------------------
extern "C" void kernel_launch(void* const* d_in, const int* in_sizes, int n_in,
                              void* d_out, int out_size, void* d_ws, size_t ws_size,
                              hipStream_t stream) {
    const float* x            = (const float*)d_in[0];
    const float* embed        = (const float*)d_in[1];
    const float* embed_avg    = (const float*)d_in[2];
    const float* cluster_size = (const float*)d_in[3];

    float* out       = (float*)d_out;
    float* quant     = out;                                   // [N, D]
    float* ind       = out + (size_t)N_PTS * D_DIM;           // [N]
    float* emb_norm  = ind + N_PTS;                           // [C, D]
    float* cs_out    = emb_norm + (size_t)C_CODES * D_DIM;    // [C]

    float* ws     = (float*)d_ws;
    float* counts = ws + WS_COUNTS;
    float* esum   = ws + WS_ESUM;
    float* enorm  = ws + WS_ENORM;
    float* denom  = ws + WS_DENOM;

    // zero counts + esum (ws is poisoned 0xAA before every launch)
    hipMemsetAsync(ws, 0, (size_t)(WS_ESUM + C_CODES * D_DIM) * sizeof(float), stream);

    vq_enorm<<<C_CODES / 4, 256, 0, stream>>>(embed, enorm);
    vq_main<<<N_PTS / 64, 256, 0, stream>>>(x, embed, enorm, quant, ind, counts, esum);
    vq_fin1<<<1, 1024, 0, stream>>>(cluster_size, counts, cs_out, denom);
    vq_fin2<<<(C_CODES * D_DIM / 4) / 256, 256, 0, stream>>>(embed_avg, esum, denom, emb_norm);
}

// Round 3
// 442.104 us; speedup vs baseline: 1.2361x; 1.2361x over previous
//
#include <hip/hip_runtime.h>
#include <cstdint>

#define DECAY 0.99f
#define OMD   0.01f
#define EPSV  1e-5f

constexpr int N_PTS   = 32768;  // B*T
constexpr int D_DIM   = 256;
constexpr int C_CODES = 1024;
constexpr int KPACK   = 768;    // 3*D for the split GEMM

typedef _Float16 half8  __attribute__((ext_vector_type(8)));
typedef _Float16 half4v __attribute__((ext_vector_type(4)));
typedef float    floatx4 __attribute__((ext_vector_type(4)));

// workspace layout (float offsets)
constexpr size_t WS_COUNTS = 0;                            // [1024]
constexpr size_t WS_ESUM   = 1024;                         // [1024*256]
constexpr size_t WS_ENORM  = WS_ESUM + 1024 * 256;         // [1024]
constexpr size_t WS_DENOM  = WS_ENORM + 1024;              // [1024]
constexpr size_t WS_CAND   = WS_DENOM + 1024;              // float2[32768*16] = 1048576 floats
constexpr size_t WS_A16    = WS_CAND + 1048576;            // half[32768*768] = 12582912 floats
constexpr size_t WS_B16    = WS_A16 + 12582912;            // half[1024*768]  = 393216 floats
constexpr size_t WS_TOTAL_FLOATS = WS_B16 + 393216;

__device__ __forceinline__ void async_copy16(const void* g, void* s) {
    __builtin_amdgcn_global_load_lds(
        (const __attribute__((address_space(1))) unsigned int*)(uintptr_t)g,
        (__attribute__((address_space(3))) unsigned int*)(uintptr_t)s, 16, 0, 0);
}

// ---------------------------------------------------------------------------
// Split x (fp32) into [xh | xh | xl] fp16 rows of length 768.
__global__ __launch_bounds__(256) void vq_prep_x(const float* __restrict__ X,
                                                 _Float16* __restrict__ A) {
    int i = blockIdx.x * 256 + threadIdx.x;          // float4 index, N*D/4 total
    int n = i >> 6, kq = (i & 63) * 4;
    float4 v = reinterpret_cast<const float4*>(X)[i];
    _Float16 h0 = (_Float16)v.x, h1 = (_Float16)v.y, h2 = (_Float16)v.z, h3 = (_Float16)v.w;
    _Float16 l0 = (_Float16)(v.x - (float)h0), l1 = (_Float16)(v.y - (float)h1);
    _Float16 l2 = (_Float16)(v.z - (float)h2), l3 = (_Float16)(v.w - (float)h3);
    half4v hi = {h0, h1, h2, h3};
    half4v lo = {l0, l1, l2, l3};
    _Float16* row = A + (size_t)n * KPACK;
    *reinterpret_cast<half4v*>(row + kq)       = hi;
    *reinterpret_cast<half4v*>(row + 256 + kq) = hi;
    *reinterpret_cast<half4v*>(row + 512 + kq) = lo;
}

// Split e into [eh | el | eh] fp16 rows of length 768.
__global__ __launch_bounds__(256) void vq_prep_e(const float* __restrict__ E,
                                                 _Float16* __restrict__ B) {
    int i = blockIdx.x * 256 + threadIdx.x;          // float4 index, C*D/4 total
    int c = i >> 6, kq = (i & 63) * 4;
    float4 v = reinterpret_cast<const float4*>(E)[i];
    _Float16 h0 = (_Float16)v.x, h1 = (_Float16)v.y, h2 = (_Float16)v.z, h3 = (_Float16)v.w;
    _Float16 l0 = (_Float16)(v.x - (float)h0), l1 = (_Float16)(v.y - (float)h1);
    _Float16 l2 = (_Float16)(v.z - (float)h2), l3 = (_Float16)(v.w - (float)h3);
    half4v hi = {h0, h1, h2, h3};
    half4v lo = {l0, l1, l2, l3};
    _Float16* row = B + (size_t)c * KPACK;
    *reinterpret_cast<half4v*>(row + kq)       = hi;
    *reinterpret_cast<half4v*>(row + 256 + kq) = lo;
    *reinterpret_cast<half4v*>(row + 512 + kq) = hi;
}

// enorm[c] = sum_d embed[c,d]^2 (fp32-exact). One wave per code.
__global__ __launch_bounds__(256) void vq_enorm(const float* __restrict__ E,
                                                float* __restrict__ enorm) {
    int c    = blockIdx.x * 4 + (threadIdx.x >> 6);
    int lane = threadIdx.x & 63;
    float4 v = reinterpret_cast<const float4*>(E)[c * 64 + lane];
    float s  = v.x * v.x + v.y * v.y + v.z * v.z + v.w * v.w;
#pragma unroll
    for (int off = 32; off > 0; off >>= 1) s += __shfl_down(s, off, 64);
    if (lane == 0) enorm[c] = s;
}

// ---------------------------------------------------------------------------
// MFMA GEMM: 128 rows x 128 codes per block, K=768 fp16, fused per-block
// row-argmax (over the block's 128 codes) -> candidate (val, idx) per row.
__global__ __launch_bounds__(256, 2) void vq_gemm(
    const _Float16* __restrict__ A, const _Float16* __restrict__ B,
    const float* __restrict__ enorm, float2* __restrict__ cand) {
    __shared__ _Float16 As[128 * 64];   // [row][k], 16B chunks XOR-swizzled by row&7
    __shared__ _Float16 Bs[128 * 64];

    const int tid = threadIdx.x;
    const int w   = tid >> 6;           // wave 0..3
    const int l   = tid & 63;
    const int n0  = blockIdx.y * 128;   // row block
    const int cb0 = blockIdx.x * 128;   // code block

    // staging: wave w stages rows [w*32, w*32+32) of both tiles, 4 loads of 8 rows
    const int srow = l >> 3;                 // 0..7 within 8-row group
    const int sq   = (l & 7) ^ srow;         // logical 16B chunk (swizzle)

    floatx4 acc[4][4] = {};

    for (int k0 = 0; k0 < KPACK; k0 += 64) {
        __syncthreads();
#pragma unroll
        for (int t = 0; t < 4; ++t) {
            int rr = w * 32 + t * 8;
            const _Float16* ga = A + (size_t)(n0 + rr + srow) * KPACK + k0 + sq * 8;
            async_copy16(ga, &As[rr * 64]);
            const _Float16* gb = B + (size_t)(cb0 + rr + srow) * KPACK + k0 + sq * 8;
            async_copy16(gb, &Bs[rr * 64]);
        }
        __syncthreads();
#pragma unroll
        for (int kk = 0; kk < 2; ++kk) {
            half8 af[4], bf[4];
            int qa = kk * 4 + (l >> 4);      // logical chunk 0..7
#pragma unroll
            for (int i = 0; i < 4; ++i) {
                int row  = (w & 1) * 64 + 16 * i + (l & 15);
                af[i] = *reinterpret_cast<const half8*>(&As[row * 64 + (qa ^ (row & 7)) * 8]);
                int crow = (w >> 1) * 64 + 16 * i + (l & 15);
                bf[i] = *reinterpret_cast<const half8*>(&Bs[crow * 64 + (qa ^ (crow & 7)) * 8]);
            }
#pragma unroll
            for (int i = 0; i < 4; ++i)
#pragma unroll
                for (int j = 0; j < 4; ++j)
                    acc[i][j] = __builtin_amdgcn_mfma_f32_16x16x32_f16(af[i], bf[j], acc[i][j], 0, 0, 0);
        }
    }

    // epilogue: dist = 2*acc - enorm[col]; argmax over this wave's 64 cols.
    const int colbase = cb0 + (w >> 1) * 64 + (l & 15);
    float en[4];
#pragma unroll
    for (int j = 0; j < 4; ++j) en[j] = enorm[colbase + 16 * j];

#pragma unroll
    for (int i = 0; i < 4; ++i) {
#pragma unroll
        for (int reg = 0; reg < 4; ++reg) {
            float bv = -3.4e38f;
            int   bi = 0x7fffffff;
#pragma unroll
            for (int j = 0; j < 4; ++j) {
                float v = 2.0f * acc[i][j][reg] - en[j];
                int   c = colbase + 16 * j;
                if (v > bv || (v == bv && c < bi)) { bv = v; bi = c; }
            }
            // butterfly over the 16 column-lanes (low 4 bits of lane id)
#pragma unroll
            for (int s = 1; s < 16; s <<= 1) {
                float ov = __shfl_xor(bv, s, 64);
                int   oi = __shfl_xor(bi, s, 64);
                if (ov > bv || (ov == bv && oi < bi)) { bv = ov; bi = oi; }
            }
            if ((l & 15) == 0) {
                int row = n0 + (w & 1) * 64 + 16 * i + (l >> 4) * 4 + reg;
                cand[(size_t)row * 16 + blockIdx.x * 2 + (w >> 1)] = make_float2(bv, (float)bi);
            }
        }
    }
}

// ---------------------------------------------------------------------------
// Merge 16 candidates/row -> index; then gather quantize, histogram, scatter x.
__global__ __launch_bounds__(256) void vq_merge(
    const float2* __restrict__ cand, const float* __restrict__ X,
    const float* __restrict__ E, float* __restrict__ quant,
    float* __restrict__ indout, float* __restrict__ counts,
    float* __restrict__ esum) {
    __shared__ int rowsel[64];
    const int tid = threadIdx.x;
    const int n0  = blockIdx.x * 64;

    if (tid < 64) {
        int r = n0 + tid;
        float bv = -3.4e38f;
        int   bi = 0x7fffffff;
#pragma unroll
        for (int t = 0; t < 16; ++t) {       // slot order == ascending code ranges
            float2 cv = cand[(size_t)r * 16 + t];
            int ci = (int)cv.y;
            if (cv.x > bv || (cv.x == bv && ci < bi)) { bv = cv.x; bi = ci; }
        }
        rowsel[tid] = bi;
        indout[r]   = (float)bi;
        unsafeAtomicAdd(&counts[bi], 1.0f);
    }
    __syncthreads();

    const float4* X4 = reinterpret_cast<const float4*>(X);
    const float4* E4 = reinterpret_cast<const float4*>(E);
    float4*       Q4 = reinterpret_cast<float4*>(quant);
    const int lane = tid & 63;
#pragma unroll
    for (int it = 0; it < 16; ++it) {
        int r   = (tid >> 6) + 4 * it;
        int idx = rowsel[r];
        float4 ev = E4[idx * 64 + lane];
        Q4[(n0 + r) * 64 + lane] = ev;
        float4 xv = X4[(n0 + r) * 64 + lane];
        float* dst = &esum[idx * D_DIM + lane * 4];
        unsafeAtomicAdd(dst + 0, xv.x);
        unsafeAtomicAdd(dst + 1, xv.y);
        unsafeAtomicAdd(dst + 2, xv.z);
        unsafeAtomicAdd(dst + 3, xv.w);
    }
}

// ---------------------------------------------------------------------------
// FALLBACK (proven R1 path): fp32 VALU tiled GEMM + fused epilogue.
__global__ __launch_bounds__(256) void vq_main_fb(
    const float* __restrict__ X, const float* __restrict__ E,
    const float* __restrict__ enorm,
    float* __restrict__ quant, float* __restrict__ indout,
    float* __restrict__ counts, float* __restrict__ esum) {
    constexpr int BN = 64, BC = 64, BK = 32, PADR = 68;
    __shared__ float As[BK * PADR];
    __shared__ float Bs[BK * PADR];
    __shared__ float redv[BN * 16];
    __shared__ int   redi[BN * 16];
    __shared__ int   rowsel[BN];

    const int tid = threadIdx.x;
    const int n0  = blockIdx.x * BN;
    const int tr  = tid >> 4;
    const int tc  = tid & 15;
    const int sr  = tid >> 2;
    const int sk  = tid & 3;

    const float4* X4 = reinterpret_cast<const float4*>(X);
    const float4* E4 = reinterpret_cast<const float4*>(E);

    float best[4];
    int   bidx[4];
#pragma unroll
    for (int i = 0; i < 4; i++) { best[i] = -3.4e38f; bidx[i] = 0; }

    for (int c0 = 0; c0 < C_CODES; c0 += BC) {
        float acc[4][4] = {};
        for (int k0 = 0; k0 < D_DIM; k0 += BK) {
            __syncthreads();
#pragma unroll
            for (int it = 0; it < 2; ++it) {
                int   k4 = sk + 4 * it;
                float4 av = X4[(n0 + sr) * 64 + (k0 >> 2) + k4];
                float4 bv = E4[(c0 + sr) * 64 + (k0 >> 2) + k4];
                int kk = k4 * 4;
                As[(kk + 0) * PADR + sr] = av.x;
                As[(kk + 1) * PADR + sr] = av.y;
                As[(kk + 2) * PADR + sr] = av.z;
                As[(kk + 3) * PADR + sr] = av.w;
                Bs[(kk + 0) * PADR + sr] = bv.x;
                Bs[(kk + 1) * PADR + sr] = bv.y;
                Bs[(kk + 2) * PADR + sr] = bv.z;
                Bs[(kk + 3) * PADR + sr] = bv.w;
            }
            __syncthreads();
#pragma unroll
            for (int k = 0; k < BK; ++k) {
                float4 a = *reinterpret_cast<const float4*>(&As[k * PADR + 4 * tr]);
                float4 b = *reinterpret_cast<const float4*>(&Bs[k * PADR + 4 * tc]);
                acc[0][0] += a.x * b.x; acc[0][1] += a.x * b.y;
                acc[0][2] += a.x * b.z; acc[0][3] += a.x * b.w;
                acc[1][0] += a.y * b.x; acc[1][1] += a.y * b.y;
                acc[1][2] += a.y * b.z; acc[1][3] += a.y * b.w;
                acc[2][0] += a.z * b.x; acc[2][1] += a.z * b.y;
                acc[2][2] += a.z * b.z; acc[2][3] += a.z * b.w;
                acc[3][0] += a.w * b.x; acc[3][1] += a.w * b.y;
                acc[3][2] += a.w * b.z; acc[3][3] += a.w * b.w;
            }
        }
        float4 en = *reinterpret_cast<const float4*>(&enorm[c0 + 4 * tc]);
        float enj[4] = {en.x, en.y, en.z, en.w};
#pragma unroll
        for (int i = 0; i < 4; i++)
#pragma unroll
            for (int j = 0; j < 4; j++) {
                float v = 2.0f * acc[i][j] - enj[j];
                int   c = c0 + 4 * tc + j;
                if (v > best[i]) { best[i] = v; bidx[i] = c; }
            }
    }

    __syncthreads();
#pragma unroll
    for (int i = 0; i < 4; i++) {
        redv[(4 * tr + i) * 16 + tc] = best[i];
        redi[(4 * tr + i) * 16 + tc] = bidx[i];
    }
    __syncthreads();
    if (tid < BN) {
        float bv = redv[tid * 16];
        int   bi = redi[tid * 16];
        for (int t = 1; t < 16; t++) {
            float v  = redv[tid * 16 + t];
            int   id = redi[tid * 16 + t];
            if (v > bv || (v == bv && id < bi)) { bv = v; bi = id; }
        }
        rowsel[tid] = bi;
        indout[n0 + tid] = (float)bi;
        unsafeAtomicAdd(&counts[bi], 1.0f);
    }
    __syncthreads();

    float4*   Q4   = reinterpret_cast<float4*>(quant);
    const int lane = tid & 63;
#pragma unroll
    for (int it = 0; it < 16; ++it) {
        int r   = (tid >> 6) + 4 * it;
        int idx = rowsel[r];
        float4 ev = E4[idx * 64 + lane];
        Q4[(n0 + r) * 64 + lane] = ev;
        float4 xv = X4[(n0 + r) * 64 + lane];
        float* dst = &esum[idx * D_DIM + lane * 4];
        unsafeAtomicAdd(dst + 0, xv.x);
        unsafeAtomicAdd(dst + 1, xv.y);
        unsafeAtomicAdd(dst + 2, xv.z);
        unsafeAtomicAdd(dst + 3, xv.w);
    }
}

// ---------------------------------------------------------------------------
__global__ __launch_bounds__(1024) void vq_fin1(const float* __restrict__ cs_in,
                                                const float* __restrict__ counts,
                                                float* __restrict__ cs_out,
                                                float* __restrict__ denom) {
    __shared__ float red[1024];
    int   c  = threadIdx.x;
    float cs = DECAY * cs_in[c] + OMD * counts[c];
    cs_out[c] = cs;
    red[c]    = cs;
    __syncthreads();
    for (int s = 512; s > 0; s >>= 1) {
        if (c < s) red[c] += red[c + s];
        __syncthreads();
    }
    float ntot = red[0];
    denom[c] = (cs + EPSV) / (ntot + (float)C_CODES * EPSV) * ntot;
}

__global__ __launch_bounds__(256) void vq_fin2(const float* __restrict__ ea,
                                               const float* __restrict__ esum,
                                               const float* __restrict__ denom,
                                               float* __restrict__ out) {
    int i = blockIdx.x * 256 + threadIdx.x;
    int c = i >> 6;
    float4 a = reinterpret_cast<const float4*>(ea)[i];
    float4 s = reinterpret_cast<const float4*>(esum)[i];
    float  d = denom[c];
    float4 o;
    o.x = (DECAY * a.x + OMD * s.x) / d;
    o.y = (DECAY * a.y + OMD * s.y) / d;
    o.z = (DECAY * a.z + OMD * s.z) / d;
    o.w = (DECAY * a.w + OMD * s.w) / d;
    reinterpret_cast<float4*>(out)[i] = o;
}

// ---------------------------------------------------------------------------
extern "C" void kernel_launch(void* const* d_in, const int* in_sizes, int n_in,
                              void* d_out, int out_size, void* d_ws, size_t ws_size,
                              hipStream_t stream) {
    const float* x            = (const float*)d_in[0];
    const float* embed        = (const float*)d_in[1];
    const float* embed_avg    = (const float*)d_in[2];
    const float* cluster_size = (const float*)d_in[3];

    float* out      = (float*)d_out;
    float* quant    = out;                                 // [N, D]
    float* ind      = out + (size_t)N_PTS * D_DIM;         // [N]
    float* emb_norm = ind + N_PTS;                         // [C, D]
    float* cs_out   = emb_norm + (size_t)C_CODES * D_DIM;  // [C]

    float*    ws     = (float*)d_ws;
    float*    counts = ws + WS_COUNTS;
    float*    esum   = ws + WS_ESUM;
    float*    enorm  = ws + WS_ENORM;
    float*    denom  = ws + WS_DENOM;

    // zero counts + esum (ws is poisoned 0xAA before every launch)
    hipMemsetAsync(ws, 0, (WS_ESUM + 1024 * 256) * sizeof(float), stream);

    vq_enorm<<<C_CODES / 4, 256, 0, stream>>>(embed, enorm);

    if (ws_size >= WS_TOTAL_FLOATS * sizeof(float)) {
        // fast path: fp16-split MFMA GEMM
        float2*   cand = (float2*)(ws + WS_CAND);
        _Float16* A16  = (_Float16*)(ws + WS_A16);
        _Float16* B16  = (_Float16*)(ws + WS_B16);
        vq_prep_x<<<N_PTS * 64 / 256, 256, 0, stream>>>(x, A16);
        vq_prep_e<<<C_CODES * 64 / 256, 256, 0, stream>>>(embed, B16);
        vq_gemm<<<dim3(C_CODES / 128, N_PTS / 128), 256, 0, stream>>>(A16, B16, enorm, cand);
        vq_merge<<<N_PTS / 64, 256, 0, stream>>>(cand, x, embed, quant, ind, counts, esum);
    } else {
        // fallback: proven fp32 VALU path (~550 us)
        vq_main_fb<<<N_PTS / 64, 256, 0, stream>>>(x, embed, enorm, quant, ind, counts, esum);
    }

    vq_fin1<<<1, 1024, 0, stream>>>(cluster_size, counts, cs_out, denom);
    vq_fin2<<<(C_CODES * D_DIM / 4) / 256, 256, 0, stream>>>(embed_avg, esum, denom, emb_norm);
}

// Round 7
// 287.709 us; speedup vs baseline: 1.8994x; 1.5366x over previous
//
#include <hip/hip_runtime.h>
#include <cstdint>

#define DECAY 0.99f
#define OMD   0.01f
#define EPSV  1e-5f

constexpr int N_PTS   = 32768;  // B*T
constexpr int D_DIM   = 256;
constexpr int C_CODES = 1024;
constexpr int KPACK   = 768;    // 3*D for the split GEMM

typedef _Float16 half8  __attribute__((ext_vector_type(8)));
typedef _Float16 half4v __attribute__((ext_vector_type(4)));
typedef float    floatx4 __attribute__((ext_vector_type(4)));

// workspace layout (float offsets)
constexpr size_t WS_ENORM = 0;                        // float[1024]
constexpr size_t WS_CSSUM = 1024;                     // float[64]
constexpr size_t WS_CAND  = 2048;                     // float2[32768*16] = 1048576 floats
constexpr size_t WS_A16   = WS_CAND + 1048576;        // half[32768*768] = 12582912 floats
constexpr size_t WS_B16   = WS_A16 + 12582912;        // half[1024*768]  = 393216 floats
constexpr size_t WS_TOTAL_FLOATS = WS_B16 + 393216;   // ~56.1 MB (R3 proved ws >= 57.2 MB)

__device__ __forceinline__ void async_copy16(const void* g, void* s) {
    __builtin_amdgcn_global_load_lds(
        (const __attribute__((address_space(1))) unsigned int*)(uintptr_t)g,
        (__attribute__((address_space(3))) unsigned int*)(uintptr_t)s, 16, 0, 0);
}

// ---------------------------------------------------------------------------
// Split x (fp32) into [xh | xh | xl] fp16 rows of length 768.  (R3-proven)
__global__ __launch_bounds__(256) void vq_prep_x(const float* __restrict__ X,
                                                 _Float16* __restrict__ A) {
    int i = blockIdx.x * 256 + threadIdx.x;          // float4 index, N*D/4 total
    int n = i >> 6, kq = (i & 63) * 4;
    float4 v = reinterpret_cast<const float4*>(X)[i];
    _Float16 h0 = (_Float16)v.x, h1 = (_Float16)v.y, h2 = (_Float16)v.z, h3 = (_Float16)v.w;
    _Float16 l0 = (_Float16)(v.x - (float)h0), l1 = (_Float16)(v.y - (float)h1);
    _Float16 l2 = (_Float16)(v.z - (float)h2), l3 = (_Float16)(v.w - (float)h3);
    half4v hi = {h0, h1, h2, h3};
    half4v lo = {l0, l1, l2, l3};
    _Float16* row = A + (size_t)n * KPACK;
    *reinterpret_cast<half4v*>(row + kq)       = hi;
    *reinterpret_cast<half4v*>(row + 256 + kq) = hi;
    *reinterpret_cast<half4v*>(row + 512 + kq) = lo;
}

// Split e into [eh | el | eh] fp16 rows of length 768.  (R3-proven)
__global__ __launch_bounds__(256) void vq_prep_e(const float* __restrict__ E,
                                                 _Float16* __restrict__ B) {
    int i = blockIdx.x * 256 + threadIdx.x;          // float4 index, C*D/4 total
    int c = i >> 6, kq = (i & 63) * 4;
    float4 v = reinterpret_cast<const float4*>(E)[i];
    _Float16 h0 = (_Float16)v.x, h1 = (_Float16)v.y, h2 = (_Float16)v.z, h3 = (_Float16)v.w;
    _Float16 l0 = (_Float16)(v.x - (float)h0), l1 = (_Float16)(v.y - (float)h1);
    _Float16 l2 = (_Float16)(v.z - (float)h2), l3 = (_Float16)(v.w - (float)h3);
    half4v hi = {h0, h1, h2, h3};
    half4v lo = {l0, l1, l2, l3};
    _Float16* row = B + (size_t)c * KPACK;
    *reinterpret_cast<half4v*>(row + kq)       = hi;
    *reinterpret_cast<half4v*>(row + 256 + kq) = lo;
    *reinterpret_cast<half4v*>(row + 512 + kq) = hi;
}

// enorm[c] = sum_d embed[c,d]^2 (fp32-exact). One wave per code.  (R3-proven)
__global__ __launch_bounds__(256) void vq_enorm(const float* __restrict__ E,
                                                float* __restrict__ enorm) {
    int c    = blockIdx.x * 4 + (threadIdx.x >> 6);
    int lane = threadIdx.x & 63;
    float4 v = reinterpret_cast<const float4*>(E)[c * 64 + lane];
    float s  = v.x * v.x + v.y * v.y + v.z * v.z + v.w * v.w;
#pragma unroll
    for (int off = 32; off > 0; off >>= 1) s += __shfl_down(s, off, 64);
    if (lane == 0) enorm[c] = s;
}

// cs_sum = sum(cluster_size).  One block.
__global__ __launch_bounds__(1024) void vq_cssum(const float* __restrict__ cs_in,
                                                 float* __restrict__ out) {
    __shared__ float red[1024];
    int t = threadIdx.x;
    red[t] = cs_in[t];
    __syncthreads();
    for (int s = 512; s > 0; s >>= 1) {
        if (t < s) red[t] += red[t + s];
        __syncthreads();
    }
    if (t == 0) out[0] = red[0];
}

// ---------------------------------------------------------------------------
// MFMA GEMM: 128 rows x 128 codes per block, K=768 fp16, fused per-block
// row-argmax -> candidate (val, idx) per row.  (R3-proven, unchanged)
__global__ __launch_bounds__(256, 2) void vq_gemm(
    const _Float16* __restrict__ A, const _Float16* __restrict__ B,
    const float* __restrict__ enorm, float2* __restrict__ cand) {
    __shared__ _Float16 As[128 * 64];   // [row][k], 16B chunks XOR-swizzled by row&7
    __shared__ _Float16 Bs[128 * 64];

    const int tid = threadIdx.x;
    const int w   = tid >> 6;
    const int l   = tid & 63;
    const int n0  = blockIdx.y * 128;
    const int cb0 = blockIdx.x * 128;

    const int srow = l >> 3;
    const int sq   = (l & 7) ^ srow;

    floatx4 acc[4][4] = {};

    for (int k0 = 0; k0 < KPACK; k0 += 64) {
        __syncthreads();
#pragma unroll
        for (int t = 0; t < 4; ++t) {
            int rr = w * 32 + t * 8;
            const _Float16* ga = A + (size_t)(n0 + rr + srow) * KPACK + k0 + sq * 8;
            async_copy16(ga, &As[rr * 64]);
            const _Float16* gb = B + (size_t)(cb0 + rr + srow) * KPACK + k0 + sq * 8;
            async_copy16(gb, &Bs[rr * 64]);
        }
        __syncthreads();
#pragma unroll
        for (int kk = 0; kk < 2; ++kk) {
            half8 af[4], bf[4];
            int qa = kk * 4 + (l >> 4);
#pragma unroll
            for (int i = 0; i < 4; ++i) {
                int row  = (w & 1) * 64 + 16 * i + (l & 15);
                af[i] = *reinterpret_cast<const half8*>(&As[row * 64 + (qa ^ (row & 7)) * 8]);
                int crow = (w >> 1) * 64 + 16 * i + (l & 15);
                bf[i] = *reinterpret_cast<const half8*>(&Bs[crow * 64 + (qa ^ (crow & 7)) * 8]);
            }
#pragma unroll
            for (int i = 0; i < 4; ++i)
#pragma unroll
                for (int j = 0; j < 4; ++j)
                    acc[i][j] = __builtin_amdgcn_mfma_f32_16x16x32_f16(af[i], bf[j], acc[i][j], 0, 0, 0);
        }
    }

    const int colbase = cb0 + (w >> 1) * 64 + (l & 15);
    float en[4];
#pragma unroll
    for (int j = 0; j < 4; ++j) en[j] = enorm[colbase + 16 * j];

#pragma unroll
    for (int i = 0; i < 4; ++i) {
#pragma unroll
        for (int reg = 0; reg < 4; ++reg) {
            float bv = -3.4e38f;
            int   bi = 0x7fffffff;
#pragma unroll
            for (int j = 0; j < 4; ++j) {
                float v = 2.0f * acc[i][j][reg] - en[j];
                int   c = colbase + 16 * j;
                if (v > bv || (v == bv && c < bi)) { bv = v; bi = c; }
            }
#pragma unroll
            for (int s = 1; s < 16; s <<= 1) {
                float ov = __shfl_xor(bv, s, 64);
                int   oi = __shfl_xor(bi, s, 64);
                if (ov > bv || (ov == bv && oi < bi)) { bv = ov; bi = oi; }
            }
            if ((l & 15) == 0) {
                int row = n0 + (w & 1) * 64 + 16 * i + (l >> 4) * 4 + reg;
                cand[(size_t)row * 16 + blockIdx.x * 2 + (w >> 1)] = make_float2(bv, (float)bi);
            }
        }
    }
}

// ---------------------------------------------------------------------------
// Merge candidates -> index; gather quantize.  NO global atomics at all.
__global__ __launch_bounds__(256) void vq_merge3(
    const float2* __restrict__ cand, const float* __restrict__ E,
    float* __restrict__ quant, float* __restrict__ indout) {
    __shared__ int rowsel[64];
    const int tid = threadIdx.x;
    const int n0  = blockIdx.x * 64;

    if (tid < 64) {
        int r = n0 + tid;
        float bv = -3.4e38f;
        int   bi = 0x7fffffff;
#pragma unroll
        for (int t = 0; t < 16; ++t) {
            float2 cv = cand[(size_t)r * 16 + t];
            int ci = (int)cv.y;
            if (cv.x > bv || (cv.x == bv && ci < bi)) { bv = cv.x; bi = ci; }
        }
        bi &= (C_CODES - 1);                 // hard bound (defensive)
        rowsel[tid] = bi;
        indout[r]   = (float)bi;
    }
    __syncthreads();

    const float4* E4 = reinterpret_cast<const float4*>(E);
    float4*       Q4 = reinterpret_cast<float4*>(quant);
    const int lane = tid & 63;
#pragma unroll
    for (int it = 0; it < 16; ++it) {
        int r   = (tid >> 6) + 4 * it;
        int idx = rowsel[r];
        Q4[(n0 + r) * 64 + lane] = E4[idx * 64 + lane];
    }
}

// ---------------------------------------------------------------------------
// Inverted-index accumulate: one block per code c scans ind[], collects its
// matching rows in an LDS list (block-local atomics only), sums them with
// coalesced row reads, writes cs_new + embed_norm.  No global atomics.
constexpr int ACH = 2048;   // inds examined per chunk (list can never overflow)
__global__ __launch_bounds__(256) void vq_accum2(
    const float* __restrict__ X, const float* __restrict__ ea,
    const float* __restrict__ cs_in, const float* __restrict__ cs_sum,
    const float* __restrict__ indf,
    float* __restrict__ emb_norm, float* __restrict__ cs_out) {
    __shared__ int list[ACH];
    __shared__ int lcnt;
    const int c = blockIdx.x;
    const int t = threadIdx.x;
    float acc = 0.0f;
    int total = 0;
    for (int s0 = 0; s0 < N_PTS; s0 += ACH) {
        if (t == 0) lcnt = 0;
        __syncthreads();
#pragma unroll
        for (int j = 0; j < ACH; j += 256) {
            int i = s0 + j + t;
            if ((int)indf[i] == c) {
                int p = atomicAdd(&lcnt, 1);   // LDS atomic, block-local
                list[p] = i;                   // p < ACH by construction
            }
        }
        __syncthreads();
        int m = lcnt;
        total += m;
        for (int r = 0; r < m; ++r)            // list[r] broadcast: conflict-free
            acc += X[(size_t)list[r] * D_DIM + t];
        __syncthreads();
    }
    float cs    = DECAY * cs_in[c] + OMD * (float)total;
    float ntot  = DECAY * cs_sum[0] + OMD * (float)N_PTS;  // sum(cs_new) closed form
    float denom = (cs + EPSV) / (ntot + (float)C_CODES * EPSV) * ntot;
    emb_norm[(size_t)c * D_DIM + t] =
        (DECAY * ea[(size_t)c * D_DIM + t] + OMD * acc) / denom;
    if (t == 0) cs_out[c] = cs;
}

// ---------------------------------------------------------------------------
// FALLBACK (R1-proven, only if ws too small): fp32 VALU GEMM + atomic epilogue.
__global__ __launch_bounds__(256) void vq_main_fb(
    const float* __restrict__ X, const float* __restrict__ E,
    const float* __restrict__ enorm,
    float* __restrict__ quant, float* __restrict__ indout,
    float* __restrict__ counts, float* __restrict__ esum) {
    constexpr int BN = 64, BC = 64, BK = 32, PADR = 68;
    __shared__ float As[BK * PADR];
    __shared__ float Bs[BK * PADR];
    __shared__ float redv[BN * 16];
    __shared__ int   redi[BN * 16];
    __shared__ int   rowsel[BN];

    const int tid = threadIdx.x;
    const int n0  = blockIdx.x * BN;
    const int tr  = tid >> 4;
    const int tc  = tid & 15;
    const int sr  = tid >> 2;
    const int sk  = tid & 3;

    const float4* X4 = reinterpret_cast<const float4*>(X);
    const float4* E4 = reinterpret_cast<const float4*>(E);

    float best[4];
    int   bidx[4];
#pragma unroll
    for (int i = 0; i < 4; i++) { best[i] = -3.4e38f; bidx[i] = 0; }

    for (int c0 = 0; c0 < C_CODES; c0 += BC) {
        float acc[4][4] = {};
        for (int k0 = 0; k0 < D_DIM; k0 += BK) {
            __syncthreads();
#pragma unroll
            for (int it = 0; it < 2; ++it) {
                int   k4 = sk + 4 * it;
                float4 av = X4[(n0 + sr) * 64 + (k0 >> 2) + k4];
                float4 bv = E4[(c0 + sr) * 64 + (k0 >> 2) + k4];
                int kk = k4 * 4;
                As[(kk + 0) * PADR + sr] = av.x;
                As[(kk + 1) * PADR + sr] = av.y;
                As[(kk + 2) * PADR + sr] = av.z;
                As[(kk + 3) * PADR + sr] = av.w;
                Bs[(kk + 0) * PADR + sr] = bv.x;
                Bs[(kk + 1) * PADR + sr] = bv.y;
                Bs[(kk + 2) * PADR + sr] = bv.z;
                Bs[(kk + 3) * PADR + sr] = bv.w;
            }
            __syncthreads();
#pragma unroll
            for (int k = 0; k < BK; ++k) {
                float4 a = *reinterpret_cast<const float4*>(&As[k * PADR + 4 * tr]);
                float4 b = *reinterpret_cast<const float4*>(&Bs[k * PADR + 4 * tc]);
                acc[0][0] += a.x * b.x; acc[0][1] += a.x * b.y;
                acc[0][2] += a.x * b.z; acc[0][3] += a.x * b.w;
                acc[1][0] += a.y * b.x; acc[1][1] += a.y * b.y;
                acc[1][2] += a.y * b.z; acc[1][3] += a.y * b.w;
                acc[2][0] += a.z * b.x; acc[2][1] += a.z * b.y;
                acc[2][2] += a.z * b.z; acc[2][3] += a.z * b.w;
                acc[3][0] += a.w * b.x; acc[3][1] += a.w * b.y;
                acc[3][2] += a.w * b.z; acc[3][3] += a.w * b.w;
            }
        }
        float4 en = *reinterpret_cast<const float4*>(&enorm[c0 + 4 * tc]);
        float enj[4] = {en.x, en.y, en.z, en.w};
#pragma unroll
        for (int i = 0; i < 4; i++)
#pragma unroll
            for (int j = 0; j < 4; j++) {
                float v = 2.0f * acc[i][j] - enj[j];
                int   c = c0 + 4 * tc + j;
                if (v > best[i]) { best[i] = v; bidx[i] = c; }
            }
    }

    __syncthreads();
#pragma unroll
    for (int i = 0; i < 4; i++) {
        redv[(4 * tr + i) * 16 + tc] = best[i];
        redi[(4 * tr + i) * 16 + tc] = bidx[i];
    }
    __syncthreads();
    if (tid < BN) {
        float bv = redv[tid * 16];
        int   bi = redi[tid * 16];
        for (int t = 1; t < 16; t++) {
            float v  = redv[tid * 16 + t];
            int   id = redi[tid * 16 + t];
            if (v > bv || (v == bv && id < bi)) { bv = v; bi = id; }
        }
        rowsel[tid] = bi;
        indout[n0 + tid] = (float)bi;
        unsafeAtomicAdd(&counts[bi], 1.0f);
    }
    __syncthreads();

    float4*   Q4   = reinterpret_cast<float4*>(quant);
    const int lane = tid & 63;
#pragma unroll
    for (int it = 0; it < 16; ++it) {
        int r   = (tid >> 6) + 4 * it;
        int idx = rowsel[r];
        float4 ev = E4[idx * 64 + lane];
        Q4[(n0 + r) * 64 + lane] = ev;
        float4 xv = X4[(n0 + r) * 64 + lane];
        float* dst = &esum[idx * D_DIM + lane * 4];
        unsafeAtomicAdd(dst + 0, xv.x);
        unsafeAtomicAdd(dst + 1, xv.y);
        unsafeAtomicAdd(dst + 2, xv.z);
        unsafeAtomicAdd(dst + 3, xv.w);
    }
}

__global__ __launch_bounds__(1024) void vq_fin1(const float* __restrict__ cs_in,
                                                const float* __restrict__ counts,
                                                float* __restrict__ cs_out,
                                                float* __restrict__ denom) {
    __shared__ float red[1024];
    int   c  = threadIdx.x;
    float cs = DECAY * cs_in[c] + OMD * counts[c];
    cs_out[c] = cs;
    red[c]    = cs;
    __syncthreads();
    for (int s = 512; s > 0; s >>= 1) {
        if (c < s) red[c] += red[c + s];
        __syncthreads();
    }
    float ntot = red[0];
    denom[c] = (cs + EPSV) / (ntot + (float)C_CODES * EPSV) * ntot;
}

__global__ __launch_bounds__(256) void vq_fin2(const float* __restrict__ ea,
                                               const float* __restrict__ esum,
                                               const float* __restrict__ denom,
                                               float* __restrict__ out) {
    int i = blockIdx.x * 256 + threadIdx.x;
    int c = i >> 6;
    float4 a = reinterpret_cast<const float4*>(ea)[i];
    float4 s = reinterpret_cast<const float4*>(esum)[i];
    float  d = denom[c];
    float4 o;
    o.x = (DECAY * a.x + OMD * s.x) / d;
    o.y = (DECAY * a.y + OMD * s.y) / d;
    o.z = (DECAY * a.z + OMD * s.z) / d;
    o.w = (DECAY * a.w + OMD * s.w) / d;
    reinterpret_cast<float4*>(out)[i] = o;
}

// ---------------------------------------------------------------------------
extern "C" void kernel_launch(void* const* d_in, const int* in_sizes, int n_in,
                              void* d_out, int out_size, void* d_ws, size_t ws_size,
                              hipStream_t stream) {
    const float* x            = (const float*)d_in[0];
    const float* embed        = (const float*)d_in[1];
    const float* embed_avg    = (const float*)d_in[2];
    const float* cluster_size = (const float*)d_in[3];

    float* out      = (float*)d_out;
    float* quant    = out;                                 // [N, D]
    float* ind      = out + (size_t)N_PTS * D_DIM;         // [N]
    float* emb_norm = ind + N_PTS;                         // [C, D]
    float* cs_out   = emb_norm + (size_t)C_CODES * D_DIM;  // [C]

    float* ws    = (float*)d_ws;
    float* enorm = ws + WS_ENORM;

    vq_enorm<<<C_CODES / 4, 256, 0, stream>>>(embed, enorm);

    if (ws_size >= WS_TOTAL_FLOATS * sizeof(float)) {
        float*    cssum = ws + WS_CSSUM;
        float2*   cand  = (float2*)(ws + WS_CAND);
        _Float16* A16   = (_Float16*)(ws + WS_A16);
        _Float16* B16   = (_Float16*)(ws + WS_B16);

        vq_cssum<<<1, 1024, 0, stream>>>(cluster_size, cssum);
        vq_prep_x<<<N_PTS * 64 / 256, 256, 0, stream>>>(x, A16);
        vq_prep_e<<<C_CODES * 64 / 256, 256, 0, stream>>>(embed, B16);
        vq_gemm<<<dim3(C_CODES / 128, N_PTS / 128), 256, 0, stream>>>(A16, B16, enorm, cand);
        vq_merge3<<<N_PTS / 64, 256, 0, stream>>>(cand, embed, quant, ind);
        vq_accum2<<<C_CODES, 256, 0, stream>>>(x, embed_avg, cluster_size, cssum,
                                               ind, emb_norm, cs_out);
    } else {
        // fallback: R1-proven fp32 VALU path (~550 us)
        float* countsf = ws + WS_CAND;                  // [1024]
        float* esum    = ws + WS_CAND + 1024;           // [1024*256]
        float* denom   = ws + WS_A16;                   // [1024]
        hipMemsetAsync(countsf, 0, (1024 + (size_t)C_CODES * D_DIM) * sizeof(float), stream);
        vq_main_fb<<<N_PTS / 64, 256, 0, stream>>>(x, embed, enorm, quant, ind, countsf, esum);
        vq_fin1<<<1, 1024, 0, stream>>>(cluster_size, countsf, cs_out, denom);
        vq_fin2<<<(C_CODES * D_DIM / 4) / 256, 256, 0, stream>>>(embed_avg, esum, denom, emb_norm);
    }
}

// Round 8
// 280.160 us; speedup vs baseline: 1.9506x; 1.0269x over previous
//
#include <hip/hip_runtime.h>
#include <cstdint>

#define DECAY 0.99f
#define OMD   0.01f
#define EPSV  1e-5f

constexpr int N_PTS   = 32768;  // B*T
constexpr int D_DIM   = 256;
constexpr int C_CODES = 1024;
constexpr int KPACK   = 768;    // 3*D for the split GEMM

typedef _Float16 half8  __attribute__((ext_vector_type(8)));
typedef _Float16 half4v __attribute__((ext_vector_type(4)));
typedef float    floatx4 __attribute__((ext_vector_type(4)));

// workspace layout (float offsets)
constexpr size_t WS_ENORM = 0;                        // float[1024]
constexpr size_t WS_CSSUM = 1024;                     // float[64]
constexpr size_t WS_CAND  = 2048;                     // float2[32768*16] = 1048576 floats
constexpr size_t WS_A16   = WS_CAND + 1048576;        // half[32768*768] = 12582912 floats
constexpr size_t WS_B16   = WS_A16 + 12582912;        // half[1024*768]  = 393216 floats
constexpr size_t WS_TOTAL_FLOATS = WS_B16 + 393216;

__device__ __forceinline__ void async_copy16(const void* g, void* s) {
    __builtin_amdgcn_global_load_lds(
        (const __attribute__((address_space(1))) unsigned int*)(uintptr_t)g,
        (__attribute__((address_space(3))) unsigned int*)(uintptr_t)s, 16, 0, 0);
}

// ---------------------------------------------------------------------------
// Split x (fp32) into [xh | xh | xl] fp16 rows of length 768.  (R3-proven)
__global__ __launch_bounds__(256) void vq_prep_x(const float* __restrict__ X,
                                                 _Float16* __restrict__ A) {
    int i = blockIdx.x * 256 + threadIdx.x;          // float4 index, N*D/4 total
    int n = i >> 6, kq = (i & 63) * 4;
    float4 v = reinterpret_cast<const float4*>(X)[i];
    _Float16 h0 = (_Float16)v.x, h1 = (_Float16)v.y, h2 = (_Float16)v.z, h3 = (_Float16)v.w;
    _Float16 l0 = (_Float16)(v.x - (float)h0), l1 = (_Float16)(v.y - (float)h1);
    _Float16 l2 = (_Float16)(v.z - (float)h2), l3 = (_Float16)(v.w - (float)h3);
    half4v hi = {h0, h1, h2, h3};
    half4v lo = {l0, l1, l2, l3};
    _Float16* row = A + (size_t)n * KPACK;
    *reinterpret_cast<half4v*>(row + kq)       = hi;
    *reinterpret_cast<half4v*>(row + 256 + kq) = hi;
    *reinterpret_cast<half4v*>(row + 512 + kq) = lo;
}

// Split e into [eh | el | eh] fp16 rows of length 768.  (R3-proven)
__global__ __launch_bounds__(256) void vq_prep_e(const float* __restrict__ E,
                                                 _Float16* __restrict__ B) {
    int i = blockIdx.x * 256 + threadIdx.x;          // float4 index, C*D/4 total
    int c = i >> 6, kq = (i & 63) * 4;
    float4 v = reinterpret_cast<const float4*>(E)[i];
    _Float16 h0 = (_Float16)v.x, h1 = (_Float16)v.y, h2 = (_Float16)v.z, h3 = (_Float16)v.w;
    _Float16 l0 = (_Float16)(v.x - (float)h0), l1 = (_Float16)(v.y - (float)h1);
    _Float16 l2 = (_Float16)(v.z - (float)h2), l3 = (_Float16)(v.w - (float)h3);
    half4v hi = {h0, h1, h2, h3};
    half4v lo = {l0, l1, l2, l3};
    _Float16* row = B + (size_t)c * KPACK;
    *reinterpret_cast<half4v*>(row + kq)       = hi;
    *reinterpret_cast<half4v*>(row + 256 + kq) = lo;
    *reinterpret_cast<half4v*>(row + 512 + kq) = hi;
}

// enorm[c] = sum_d embed[c,d]^2 (fp32-exact). One wave per code.  (R3-proven)
__global__ __launch_bounds__(256) void vq_enorm(const float* __restrict__ E,
                                                float* __restrict__ enorm) {
    int c    = blockIdx.x * 4 + (threadIdx.x >> 6);
    int lane = threadIdx.x & 63;
    float4 v = reinterpret_cast<const float4*>(E)[c * 64 + lane];
    float s  = v.x * v.x + v.y * v.y + v.z * v.z + v.w * v.w;
#pragma unroll
    for (int off = 32; off > 0; off >>= 1) s += __shfl_down(s, off, 64);
    if (lane == 0) enorm[c] = s;
}

// cs_sum = sum(cluster_size).  One block.
__global__ __launch_bounds__(1024) void vq_cssum(const float* __restrict__ cs_in,
                                                 float* __restrict__ out) {
    __shared__ float red[1024];
    int t = threadIdx.x;
    red[t] = cs_in[t];
    __syncthreads();
    for (int s = 512; s > 0; s >>= 1) {
        if (t < s) red[t] += red[t + s];
        __syncthreads();
    }
    if (t == 0) out[0] = red[0];
}

// ---------------------------------------------------------------------------
// MFMA GEMM: 128 rows x 128 codes per block, K=768 fp16, fused per-block
// row-argmax -> candidate (val, idx) per row.  (R3-proven, unchanged)
__global__ __launch_bounds__(256, 2) void vq_gemm(
    const _Float16* __restrict__ A, const _Float16* __restrict__ B,
    const float* __restrict__ enorm, float2* __restrict__ cand) {
    __shared__ _Float16 As[128 * 64];   // [row][k], 16B chunks XOR-swizzled by row&7
    __shared__ _Float16 Bs[128 * 64];

    const int tid = threadIdx.x;
    const int w   = tid >> 6;
    const int l   = tid & 63;
    const int n0  = blockIdx.y * 128;
    const int cb0 = blockIdx.x * 128;

    const int srow = l >> 3;
    const int sq   = (l & 7) ^ srow;

    floatx4 acc[4][4] = {};

    for (int k0 = 0; k0 < KPACK; k0 += 64) {
        __syncthreads();
#pragma unroll
        for (int t = 0; t < 4; ++t) {
            int rr = w * 32 + t * 8;
            const _Float16* ga = A + (size_t)(n0 + rr + srow) * KPACK + k0 + sq * 8;
            async_copy16(ga, &As[rr * 64]);
            const _Float16* gb = B + (size_t)(cb0 + rr + srow) * KPACK + k0 + sq * 8;
            async_copy16(gb, &Bs[rr * 64]);
        }
        __syncthreads();
#pragma unroll
        for (int kk = 0; kk < 2; ++kk) {
            half8 af[4], bf[4];
            int qa = kk * 4 + (l >> 4);
#pragma unroll
            for (int i = 0; i < 4; ++i) {
                int row  = (w & 1) * 64 + 16 * i + (l & 15);
                af[i] = *reinterpret_cast<const half8*>(&As[row * 64 + (qa ^ (row & 7)) * 8]);
                int crow = (w >> 1) * 64 + 16 * i + (l & 15);
                bf[i] = *reinterpret_cast<const half8*>(&Bs[crow * 64 + (qa ^ (crow & 7)) * 8]);
            }
#pragma unroll
            for (int i = 0; i < 4; ++i)
#pragma unroll
                for (int j = 0; j < 4; ++j)
                    acc[i][j] = __builtin_amdgcn_mfma_f32_16x16x32_f16(af[i], bf[j], acc[i][j], 0, 0, 0);
        }
    }

    const int colbase = cb0 + (w >> 1) * 64 + (l & 15);
    float en[4];
#pragma unroll
    for (int j = 0; j < 4; ++j) en[j] = enorm[colbase + 16 * j];

#pragma unroll
    for (int i = 0; i < 4; ++i) {
#pragma unroll
        for (int reg = 0; reg < 4; ++reg) {
            float bv = -3.4e38f;
            int   bi = 0x7fffffff;
#pragma unroll
            for (int j = 0; j < 4; ++j) {
                float v = 2.0f * acc[i][j][reg] - en[j];
                int   c = colbase + 16 * j;
                if (v > bv || (v == bv && c < bi)) { bv = v; bi = c; }
            }
#pragma unroll
            for (int s = 1; s < 16; s <<= 1) {
                float ov = __shfl_xor(bv, s, 64);
                int   oi = __shfl_xor(bi, s, 64);
                if (ov > bv || (ov == bv && oi < bi)) { bv = ov; bi = oi; }
            }
            if ((l & 15) == 0) {
                int row = n0 + (w & 1) * 64 + 16 * i + (l >> 4) * 4 + reg;
                cand[(size_t)row * 16 + blockIdx.x * 2 + (w >> 1)] = make_float2(bv, (float)bi);
            }
        }
    }
}

// ---------------------------------------------------------------------------
// Merge candidates -> index; gather quantize.  NO global atomics.  (R7-proven)
__global__ __launch_bounds__(256) void vq_merge3(
    const float2* __restrict__ cand, const float* __restrict__ E,
    float* __restrict__ quant, float* __restrict__ indout) {
    __shared__ int rowsel[64];
    const int tid = threadIdx.x;
    const int n0  = blockIdx.x * 64;

    if (tid < 64) {
        int r = n0 + tid;
        float bv = -3.4e38f;
        int   bi = 0x7fffffff;
#pragma unroll
        for (int t = 0; t < 16; ++t) {
            float2 cv = cand[(size_t)r * 16 + t];
            int ci = (int)cv.y;
            if (cv.x > bv || (cv.x == bv && ci < bi)) { bv = cv.x; bi = ci; }
        }
        bi &= (C_CODES - 1);                 // hard bound (defensive)
        rowsel[tid] = bi;
        indout[r]   = (float)bi;
    }
    __syncthreads();

    const float4* E4 = reinterpret_cast<const float4*>(E);
    float4*       Q4 = reinterpret_cast<float4*>(quant);
    const int lane = tid & 63;
#pragma unroll
    for (int it = 0; it < 16; ++it) {
        int r   = (tid >> 6) + 4 * it;
        int idx = rowsel[r];
        Q4[(n0 + r) * 64 + lane] = E4[idx * 64 + lane];
    }
}

// ---------------------------------------------------------------------------
// Inverted-index accumulate v3: single-pass barrier-free scan into one big
// LDS list, then 8-way-ILP row sum.  Block-local LDS atomics only.
constexpr int LCAP = 8192;   // 32 KB LDS list; ~256x expected per-code count
__global__ __launch_bounds__(256) void vq_accum3(
    const float* __restrict__ X, const float* __restrict__ ea,
    const float* __restrict__ cs_in, const float* __restrict__ cs_sum,
    const float* __restrict__ indf,
    float* __restrict__ emb_norm, float* __restrict__ cs_out) {
    __shared__ int list[LCAP];
    __shared__ int lcnt;
    const int c = blockIdx.x;
    const int t = threadIdx.x;
    if (t == 0) lcnt = 0;
    __syncthreads();
    // single sweep, coalesced, no barriers inside: loads stay in flight
#pragma unroll 16
    for (int j = 0; j < N_PTS; j += 256) {
        int i = j + t;
        if ((int)indf[i] == c) {
            int p = atomicAdd(&lcnt, 1);     // LDS atomic, block-local
            if (p < LCAP) list[p] = i;
        }
    }
    __syncthreads();
    int total = lcnt;
    int m = (total < LCAP) ? total : LCAP;
    // 8-way independent accumulators -> 8 coalesced row loads in flight
    float a0 = 0, a1 = 0, a2 = 0, a3 = 0, a4 = 0, a5 = 0, a6 = 0, a7 = 0;
    int r = 0;
    for (; r + 7 < m; r += 8) {
        int i0 = list[r + 0], i1 = list[r + 1], i2 = list[r + 2], i3 = list[r + 3];
        int i4 = list[r + 4], i5 = list[r + 5], i6 = list[r + 6], i7 = list[r + 7];
        a0 += X[(size_t)i0 * D_DIM + t];
        a1 += X[(size_t)i1 * D_DIM + t];
        a2 += X[(size_t)i2 * D_DIM + t];
        a3 += X[(size_t)i3 * D_DIM + t];
        a4 += X[(size_t)i4 * D_DIM + t];
        a5 += X[(size_t)i5 * D_DIM + t];
        a6 += X[(size_t)i6 * D_DIM + t];
        a7 += X[(size_t)i7 * D_DIM + t];
    }
    for (; r < m; ++r) a0 += X[(size_t)list[r] * D_DIM + t];
    float acc = ((a0 + a1) + (a2 + a3)) + ((a4 + a5) + (a6 + a7));

    float cs    = DECAY * cs_in[c] + OMD * (float)total;
    float ntot  = DECAY * cs_sum[0] + OMD * (float)N_PTS;  // sum(cs_new) closed form
    float denom = (cs + EPSV) / (ntot + (float)C_CODES * EPSV) * ntot;
    emb_norm[(size_t)c * D_DIM + t] =
        (DECAY * ea[(size_t)c * D_DIM + t] + OMD * acc) / denom;
    if (t == 0) cs_out[c] = cs;
}

// ---------------------------------------------------------------------------
// FALLBACK (R1-proven, only if ws too small): fp32 VALU GEMM + atomic epilogue.
__global__ __launch_bounds__(256) void vq_main_fb(
    const float* __restrict__ X, const float* __restrict__ E,
    const float* __restrict__ enorm,
    float* __restrict__ quant, float* __restrict__ indout,
    float* __restrict__ counts, float* __restrict__ esum) {
    constexpr int BN = 64, BC = 64, BK = 32, PADR = 68;
    __shared__ float As[BK * PADR];
    __shared__ float Bs[BK * PADR];
    __shared__ float redv[BN * 16];
    __shared__ int   redi[BN * 16];
    __shared__ int   rowsel[BN];

    const int tid = threadIdx.x;
    const int n0  = blockIdx.x * BN;
    const int tr  = tid >> 4;
    const int tc  = tid & 15;
    const int sr  = tid >> 2;
    const int sk  = tid & 3;

    const float4* X4 = reinterpret_cast<const float4*>(X);
    const float4* E4 = reinterpret_cast<const float4*>(E);

    float best[4];
    int   bidx[4];
#pragma unroll
    for (int i = 0; i < 4; i++) { best[i] = -3.4e38f; bidx[i] = 0; }

    for (int c0 = 0; c0 < C_CODES; c0 += BC) {
        float acc[4][4] = {};
        for (int k0 = 0; k0 < D_DIM; k0 += BK) {
            __syncthreads();
#pragma unroll
            for (int it = 0; it < 2; ++it) {
                int   k4 = sk + 4 * it;
                float4 av = X4[(n0 + sr) * 64 + (k0 >> 2) + k4];
                float4 bv = E4[(c0 + sr) * 64 + (k0 >> 2) + k4];
                int kk = k4 * 4;
                As[(kk + 0) * PADR + sr] = av.x;
                As[(kk + 1) * PADR + sr] = av.y;
                As[(kk + 2) * PADR + sr] = av.z;
                As[(kk + 3) * PADR + sr] = av.w;
                Bs[(kk + 0) * PADR + sr] = bv.x;
                Bs[(kk + 1) * PADR + sr] = bv.y;
                Bs[(kk + 2) * PADR + sr] = bv.z;
                Bs[(kk + 3) * PADR + sr] = bv.w;
            }
            __syncthreads();
#pragma unroll
            for (int k = 0; k < BK; ++k) {
                float4 a = *reinterpret_cast<const float4*>(&As[k * PADR + 4 * tr]);
                float4 b = *reinterpret_cast<const float4*>(&Bs[k * PADR + 4 * tc]);
                acc[0][0] += a.x * b.x; acc[0][1] += a.x * b.y;
                acc[0][2] += a.x * b.z; acc[0][3] += a.x * b.w;
                acc[1][0] += a.y * b.x; acc[1][1] += a.y * b.y;
                acc[1][2] += a.y * b.z; acc[1][3] += a.y * b.w;
                acc[2][0] += a.z * b.x; acc[2][1] += a.z * b.y;
                acc[2][2] += a.z * b.z; acc[2][3] += a.z * b.w;
                acc[3][0] += a.w * b.x; acc[3][1] += a.w * b.y;
                acc[3][2] += a.w * b.z; acc[3][3] += a.w * b.w;
            }
        }
        float4 en = *reinterpret_cast<const float4*>(&enorm[c0 + 4 * tc]);
        float enj[4] = {en.x, en.y, en.z, en.w};
#pragma unroll
        for (int i = 0; i < 4; i++)
#pragma unroll
            for (int j = 0; j < 4; j++) {
                float v = 2.0f * acc[i][j] - enj[j];
                int   c = c0 + 4 * tc + j;
                if (v > best[i]) { best[i] = v; bidx[i] = c; }
            }
    }

    __syncthreads();
#pragma unroll
    for (int i = 0; i < 4; i++) {
        redv[(4 * tr + i) * 16 + tc] = best[i];
        redi[(4 * tr + i) * 16 + tc] = bidx[i];
    }
    __syncthreads();
    if (tid < BN) {
        float bv = redv[tid * 16];
        int   bi = redi[tid * 16];
        for (int t = 1; t < 16; t++) {
            float v  = redv[tid * 16 + t];
            int   id = redi[tid * 16 + t];
            if (v > bv || (v == bv && id < bi)) { bv = v; bi = id; }
        }
        rowsel[tid] = bi;
        indout[n0 + tid] = (float)bi;
        unsafeAtomicAdd(&counts[bi], 1.0f);
    }
    __syncthreads();

    float4*   Q4   = reinterpret_cast<float4*>(quant);
    const int lane = tid & 63;
#pragma unroll
    for (int it = 0; it < 16; ++it) {
        int r   = (tid >> 6) + 4 * it;
        int idx = rowsel[r];
        float4 ev = E4[idx * 64 + lane];
        Q4[(n0 + r) * 64 + lane] = ev;
        float4 xv = X4[(n0 + r) * 64 + lane];
        float* dst = &esum[idx * D_DIM + lane * 4];
        unsafeAtomicAdd(dst + 0, xv.x);
        unsafeAtomicAdd(dst + 1, xv.y);
        unsafeAtomicAdd(dst + 2, xv.z);
        unsafeAtomicAdd(dst + 3, xv.w);
    }
}

__global__ __launch_bounds__(1024) void vq_fin1(const float* __restrict__ cs_in,
                                                const float* __restrict__ counts,
                                                float* __restrict__ cs_out,
                                                float* __restrict__ denom) {
    __shared__ float red[1024];
    int   c  = threadIdx.x;
    float cs = DECAY * cs_in[c] + OMD * counts[c];
    cs_out[c] = cs;
    red[c]    = cs;
    __syncthreads();
    for (int s = 512; s > 0; s >>= 1) {
        if (c < s) red[c] += red[c + s];
        __syncthreads();
    }
    float ntot = red[0];
    denom[c] = (cs + EPSV) / (ntot + (float)C_CODES * EPSV) * ntot;
}

__global__ __launch_bounds__(256) void vq_fin2(const float* __restrict__ ea,
                                               const float* __restrict__ esum,
                                               const float* __restrict__ denom,
                                               float* __restrict__ out) {
    int i = blockIdx.x * 256 + threadIdx.x;
    int c = i >> 6;
    float4 a = reinterpret_cast<const float4*>(ea)[i];
    float4 s = reinterpret_cast<const float4*>(esum)[i];
    float  d = denom[c];
    float4 o;
    o.x = (DECAY * a.x + OMD * s.x) / d;
    o.y = (DECAY * a.y + OMD * s.y) / d;
    o.z = (DECAY * a.z + OMD * s.z) / d;
    o.w = (DECAY * a.w + OMD * s.w) / d;
    reinterpret_cast<float4*>(out)[i] = o;
}

// ---------------------------------------------------------------------------
extern "C" void kernel_launch(void* const* d_in, const int* in_sizes, int n_in,
                              void* d_out, int out_size, void* d_ws, size_t ws_size,
                              hipStream_t stream) {
    const float* x            = (const float*)d_in[0];
    const float* embed        = (const float*)d_in[1];
    const float* embed_avg    = (const float*)d_in[2];
    const float* cluster_size = (const float*)d_in[3];

    float* out      = (float*)d_out;
    float* quant    = out;                                 // [N, D]
    float* ind      = out + (size_t)N_PTS * D_DIM;         // [N]
    float* emb_norm = ind + N_PTS;                         // [C, D]
    float* cs_out   = emb_norm + (size_t)C_CODES * D_DIM;  // [C]

    float* ws    = (float*)d_ws;
    float* enorm = ws + WS_ENORM;

    vq_enorm<<<C_CODES / 4, 256, 0, stream>>>(embed, enorm);

    if (ws_size >= WS_TOTAL_FLOATS * sizeof(float)) {
        float*    cssum = ws + WS_CSSUM;
        float2*   cand  = (float2*)(ws + WS_CAND);
        _Float16* A16   = (_Float16*)(ws + WS_A16);
        _Float16* B16   = (_Float16*)(ws + WS_B16);

        vq_cssum<<<1, 1024, 0, stream>>>(cluster_size, cssum);
        vq_prep_x<<<N_PTS * 64 / 256, 256, 0, stream>>>(x, A16);
        vq_prep_e<<<C_CODES * 64 / 256, 256, 0, stream>>>(embed, B16);
        vq_gemm<<<dim3(C_CODES / 128, N_PTS / 128), 256, 0, stream>>>(A16, B16, enorm, cand);
        vq_merge3<<<N_PTS / 64, 256, 0, stream>>>(cand, embed, quant, ind);
        vq_accum3<<<C_CODES, 256, 0, stream>>>(x, embed_avg, cluster_size, cssum,
                                               ind, emb_norm, cs_out);
    } else {
        // fallback: R1-proven fp32 VALU path (~550 us)
        float* countsf = ws + WS_CAND;                  // [1024]
        float* esum    = ws + WS_CAND + 1024;           // [1024*256]
        float* denom   = ws + WS_A16;                   // [1024]
        hipMemsetAsync(countsf, 0, (1024 + (size_t)C_CODES * D_DIM) * sizeof(float), stream);
        vq_main_fb<<<N_PTS / 64, 256, 0, stream>>>(x, embed, enorm, quant, ind, countsf, esum);
        vq_fin1<<<1, 1024, 0, stream>>>(cluster_size, countsf, cs_out, denom);
        vq_fin2<<<(C_CODES * D_DIM / 4) / 256, 256, 0, stream>>>(embed_avg, esum, denom, emb_norm);
    }
}

// Round 9
// 229.295 us; speedup vs baseline: 2.3833x; 1.2218x over previous
//
#include <hip/hip_runtime.h>
#include <cstdint>

#define DECAY 0.99f
#define OMD   0.01f
#define EPSV  1e-5f

constexpr int N_PTS   = 32768;  // B*T
constexpr int D_DIM   = 256;
constexpr int C_CODES = 1024;
constexpr int KPACK   = 768;    // 3*D for the split GEMM

constexpr int PG = 4;           // ind chunks
constexpr int PK = 8;           // codes per partial block
constexpr int LCAP = 8192;      // worst-case list (chunk size), exact bound

typedef _Float16 half8  __attribute__((ext_vector_type(8)));
typedef _Float16 half4v __attribute__((ext_vector_type(4)));
typedef float    floatx4 __attribute__((ext_vector_type(4)));

// workspace layout (float offsets)
constexpr size_t WS_ENORM = 0;                        // float[1024]
constexpr size_t WS_CSSUM = 1024;                     // float[64]
constexpr size_t WS_PCNT  = 2048;                     // int[4*1024]
constexpr size_t WS_CAND  = 8192;                     // float2[32768*16] = 1048576 floats; later aliased by P[4][1024][256] (exact fit)
constexpr size_t WS_A16   = WS_CAND + 1048576;        // half[32768*768] = 12582912 floats
constexpr size_t WS_B16   = WS_A16 + 12582912;        // half[1024*768]  = 393216 floats
constexpr size_t WS_TOTAL_FLOATS = WS_B16 + 393216;

__device__ __forceinline__ void async_copy16(const void* g, void* s) {
    __builtin_amdgcn_global_load_lds(
        (const __attribute__((address_space(1))) unsigned int*)(uintptr_t)g,
        (__attribute__((address_space(3))) unsigned int*)(uintptr_t)s, 16, 0, 0);
}

// ---------------------------------------------------------------------------
// Split x (fp32) into [xh | xh | xl] fp16 rows of length 768.  (R3-proven)
__global__ __launch_bounds__(256) void vq_prep_x(const float* __restrict__ X,
                                                 _Float16* __restrict__ A) {
    int i = blockIdx.x * 256 + threadIdx.x;          // float4 index, N*D/4 total
    int n = i >> 6, kq = (i & 63) * 4;
    float4 v = reinterpret_cast<const float4*>(X)[i];
    _Float16 h0 = (_Float16)v.x, h1 = (_Float16)v.y, h2 = (_Float16)v.z, h3 = (_Float16)v.w;
    _Float16 l0 = (_Float16)(v.x - (float)h0), l1 = (_Float16)(v.y - (float)h1);
    _Float16 l2 = (_Float16)(v.z - (float)h2), l3 = (_Float16)(v.w - (float)h3);
    half4v hi = {h0, h1, h2, h3};
    half4v lo = {l0, l1, l2, l3};
    _Float16* row = A + (size_t)n * KPACK;
    *reinterpret_cast<half4v*>(row + kq)       = hi;
    *reinterpret_cast<half4v*>(row + 256 + kq) = hi;
    *reinterpret_cast<half4v*>(row + 512 + kq) = lo;
}

// Split e into [eh | el | eh] fp16 rows of length 768.  (R3-proven)
__global__ __launch_bounds__(256) void vq_prep_e(const float* __restrict__ E,
                                                 _Float16* __restrict__ B) {
    int i = blockIdx.x * 256 + threadIdx.x;          // float4 index, C*D/4 total
    int c = i >> 6, kq = (i & 63) * 4;
    float4 v = reinterpret_cast<const float4*>(E)[i];
    _Float16 h0 = (_Float16)v.x, h1 = (_Float16)v.y, h2 = (_Float16)v.z, h3 = (_Float16)v.w;
    _Float16 l0 = (_Float16)(v.x - (float)h0), l1 = (_Float16)(v.y - (float)h1);
    _Float16 l2 = (_Float16)(v.z - (float)h2), l3 = (_Float16)(v.w - (float)h3);
    half4v hi = {h0, h1, h2, h3};
    half4v lo = {l0, l1, l2, l3};
    _Float16* row = B + (size_t)c * KPACK;
    *reinterpret_cast<half4v*>(row + kq)       = hi;
    *reinterpret_cast<half4v*>(row + 256 + kq) = lo;
    *reinterpret_cast<half4v*>(row + 512 + kq) = hi;
}

// enorm[c] = sum_d embed[c,d]^2 (fp32-exact). One wave per code.  (R3-proven)
__global__ __launch_bounds__(256) void vq_enorm(const float* __restrict__ E,
                                                float* __restrict__ enorm) {
    int c    = blockIdx.x * 4 + (threadIdx.x >> 6);
    int lane = threadIdx.x & 63;
    float4 v = reinterpret_cast<const float4*>(E)[c * 64 + lane];
    float s  = v.x * v.x + v.y * v.y + v.z * v.z + v.w * v.w;
#pragma unroll
    for (int off = 32; off > 0; off >>= 1) s += __shfl_down(s, off, 64);
    if (lane == 0) enorm[c] = s;
}

// cs_sum = sum(cluster_size).  One block.
__global__ __launch_bounds__(1024) void vq_cssum(const float* __restrict__ cs_in,
                                                 float* __restrict__ out) {
    __shared__ float red[1024];
    int t = threadIdx.x;
    red[t] = cs_in[t];
    __syncthreads();
    for (int s = 512; s > 0; s >>= 1) {
        if (t < s) red[t] += red[t + s];
        __syncthreads();
    }
    if (t == 0) out[0] = red[0];
}

// ---------------------------------------------------------------------------
// MFMA GEMM: 128 rows x 128 codes per block, K=768 fp16, fused per-block
// row-argmax -> candidate (val, idx) per row.  (R3-proven, unchanged)
__global__ __launch_bounds__(256, 2) void vq_gemm(
    const _Float16* __restrict__ A, const _Float16* __restrict__ B,
    const float* __restrict__ enorm, float2* __restrict__ cand) {
    __shared__ _Float16 As[128 * 64];   // [row][k], 16B chunks XOR-swizzled by row&7
    __shared__ _Float16 Bs[128 * 64];

    const int tid = threadIdx.x;
    const int w   = tid >> 6;
    const int l   = tid & 63;
    const int n0  = blockIdx.y * 128;
    const int cb0 = blockIdx.x * 128;

    const int srow = l >> 3;
    const int sq   = (l & 7) ^ srow;

    floatx4 acc[4][4] = {};

    for (int k0 = 0; k0 < KPACK; k0 += 64) {
        __syncthreads();
#pragma unroll
        for (int t = 0; t < 4; ++t) {
            int rr = w * 32 + t * 8;
            const _Float16* ga = A + (size_t)(n0 + rr + srow) * KPACK + k0 + sq * 8;
            async_copy16(ga, &As[rr * 64]);
            const _Float16* gb = B + (size_t)(cb0 + rr + srow) * KPACK + k0 + sq * 8;
            async_copy16(gb, &Bs[rr * 64]);
        }
        __syncthreads();
#pragma unroll
        for (int kk = 0; kk < 2; ++kk) {
            half8 af[4], bf[4];
            int qa = kk * 4 + (l >> 4);
#pragma unroll
            for (int i = 0; i < 4; ++i) {
                int row  = (w & 1) * 64 + 16 * i + (l & 15);
                af[i] = *reinterpret_cast<const half8*>(&As[row * 64 + (qa ^ (row & 7)) * 8]);
                int crow = (w >> 1) * 64 + 16 * i + (l & 15);
                bf[i] = *reinterpret_cast<const half8*>(&Bs[crow * 64 + (qa ^ (crow & 7)) * 8]);
            }
#pragma unroll
            for (int i = 0; i < 4; ++i)
#pragma unroll
                for (int j = 0; j < 4; ++j)
                    acc[i][j] = __builtin_amdgcn_mfma_f32_16x16x32_f16(af[i], bf[j], acc[i][j], 0, 0, 0);
        }
    }

    const int colbase = cb0 + (w >> 1) * 64 + (l & 15);
    float en[4];
#pragma unroll
    for (int j = 0; j < 4; ++j) en[j] = enorm[colbase + 16 * j];

#pragma unroll
    for (int i = 0; i < 4; ++i) {
#pragma unroll
        for (int reg = 0; reg < 4; ++reg) {
            float bv = -3.4e38f;
            int   bi = 0x7fffffff;
#pragma unroll
            for (int j = 0; j < 4; ++j) {
                float v = 2.0f * acc[i][j][reg] - en[j];
                int   c = colbase + 16 * j;
                if (v > bv || (v == bv && c < bi)) { bv = v; bi = c; }
            }
#pragma unroll
            for (int s = 1; s < 16; s <<= 1) {
                float ov = __shfl_xor(bv, s, 64);
                int   oi = __shfl_xor(bi, s, 64);
                if (ov > bv || (ov == bv && oi < bi)) { bv = ov; bi = oi; }
            }
            if ((l & 15) == 0) {
                int row = n0 + (w & 1) * 64 + 16 * i + (l >> 4) * 4 + reg;
                cand[(size_t)row * 16 + blockIdx.x * 2 + (w >> 1)] = make_float2(bv, (float)bi);
            }
        }
    }
}

// ---------------------------------------------------------------------------
// Merge candidates -> index; gather quantize.  NO global atomics.  (R7-proven)
__global__ __launch_bounds__(256) void vq_merge3(
    const float2* __restrict__ cand, const float* __restrict__ E,
    float* __restrict__ quant, float* __restrict__ indout) {
    __shared__ int rowsel[64];
    const int tid = threadIdx.x;
    const int n0  = blockIdx.x * 64;

    if (tid < 64) {
        int r = n0 + tid;
        float bv = -3.4e38f;
        int   bi = 0x7fffffff;
#pragma unroll
        for (int t = 0; t < 16; ++t) {
            float2 cv = cand[(size_t)r * 16 + t];
            int ci = (int)cv.y;
            if (cv.x > bv || (cv.x == bv && ci < bi)) { bv = cv.x; bi = ci; }
        }
        bi &= (C_CODES - 1);                 // hard bound (defensive)
        rowsel[tid] = bi;
        indout[r]   = (float)bi;
    }
    __syncthreads();

    const float4* E4 = reinterpret_cast<const float4*>(E);
    float4*       Q4 = reinterpret_cast<float4*>(quant);
    const int lane = tid & 63;
#pragma unroll
    for (int it = 0; it < 16; ++it) {
        int r   = (tid >> 6) + 4 * it;
        int idx = rowsel[r];
        Q4[(n0 + r) * 64 + lane] = E4[idx * 64 + lane];
    }
}

// ---------------------------------------------------------------------------
// Partial esum: block (cg, g) scans ind chunk g (8192 entries, 8 float4/thread)
// for its PK=8 codes, gathers matching X rows with 8-deep ILP, accumulates in
// registers, writes P[g][code][d] partial tile + per-code counts.
// All write indices affine in blockIdx -> provably bounded.
__global__ __launch_bounds__(256) void vq_part(
    const float* __restrict__ X, const float* __restrict__ indf,
    float* __restrict__ P, int* __restrict__ pcnt) {
    __shared__ int list[LCAP];
    __shared__ int cnt[PK];
    __shared__ int lcnt;
    const int cg = blockIdx.x;   // 0..127 code group
    const int g  = blockIdx.y;   // 0..3 ind chunk
    const int t  = threadIdx.x;
    if (t == 0) lcnt = 0;
    if (t < PK) cnt[t] = 0;
    __syncthreads();

    const float4* I4 = reinterpret_cast<const float4*>(indf);
    float4 v[8];
#pragma unroll
    for (int j = 0; j < 8; ++j)            // 8 independent loads, one latency round
        v[j] = I4[g * 2048 + j * 256 + t];

#pragma unroll
    for (int j = 0; j < 8; ++j) {
        int base = (g * 2048 + j * 256 + t) * 4;
        int k0 = (int)v[j].x, k1 = (int)v[j].y, k2 = (int)v[j].z, k3 = (int)v[j].w;
        if ((k0 >> 3) == cg) { int p = atomicAdd(&lcnt, 1); atomicAdd(&cnt[k0 & 7], 1); if (p < LCAP) list[p] = ((base + 0) << 3) | (k0 & 7); }
        if ((k1 >> 3) == cg) { int p = atomicAdd(&lcnt, 1); atomicAdd(&cnt[k1 & 7], 1); if (p < LCAP) list[p] = ((base + 1) << 3) | (k1 & 7); }
        if ((k2 >> 3) == cg) { int p = atomicAdd(&lcnt, 1); atomicAdd(&cnt[k2 & 7], 1); if (p < LCAP) list[p] = ((base + 2) << 3) | (k2 & 7); }
        if ((k3 >> 3) == cg) { int p = atomicAdd(&lcnt, 1); atomicAdd(&cnt[k3 & 7], 1); if (p < LCAP) list[p] = ((base + 3) << 3) | (k3 & 7); }
    }
    __syncthreads();

    int m = lcnt; if (m > LCAP) m = LCAP;
    float acc[PK] = {0, 0, 0, 0, 0, 0, 0, 0};
    int r = 0;
    for (; r + 8 <= m; r += 8) {           // 8 coalesced row loads in flight
        int e[8];
        float val[8];
#pragma unroll
        for (int q = 0; q < 8; ++q) e[q] = list[r + q];
#pragma unroll
        for (int q = 0; q < 8; ++q) val[q] = X[(size_t)(e[q] >> 3) * D_DIM + t];
#pragma unroll
        for (int q = 0; q < 8; ++q) {
            int k = e[q] & 7;
#pragma unroll
            for (int kk = 0; kk < PK; ++kk) acc[kk] += (k == kk) ? val[q] : 0.0f;
        }
    }
    for (; r < m; ++r) {
        int e = list[r];
        float val = X[(size_t)(e >> 3) * D_DIM + t];
        int k = e & 7;
#pragma unroll
        for (int kk = 0; kk < PK; ++kk) acc[kk] += (k == kk) ? val : 0.0f;
    }

#pragma unroll
    for (int kk = 0; kk < PK; ++kk)
        P[((size_t)g * C_CODES + cg * PK + kk) * D_DIM + t] = acc[kk];
    if (t < PK) pcnt[g * C_CODES + cg * PK + t] = cnt[t];
}

// ---------------------------------------------------------------------------
// Combine partials + fused EMA/laplace epilogue.  One block per code.
__global__ __launch_bounds__(256) void vq_comb(
    const float* __restrict__ P, const int* __restrict__ pcnt,
    const float* __restrict__ ea, const float* __restrict__ cs_in,
    const float* __restrict__ cs_sum,
    float* __restrict__ emb_norm, float* __restrict__ cs_out) {
    const int c = blockIdx.x;
    const int t = threadIdx.x;
    float s = 0.0f;
#pragma unroll
    for (int g = 0; g < PG; ++g)
        s += P[((size_t)g * C_CODES + c) * D_DIM + t];
    int total = pcnt[c] + pcnt[C_CODES + c] + pcnt[2 * C_CODES + c] + pcnt[3 * C_CODES + c];
    float cs    = DECAY * cs_in[c] + OMD * (float)total;
    float ntot  = DECAY * cs_sum[0] + OMD * (float)N_PTS;   // sum(cs_new) closed form
    float denom = (cs + EPSV) / (ntot + (float)C_CODES * EPSV) * ntot;
    emb_norm[(size_t)c * D_DIM + t] =
        (DECAY * ea[(size_t)c * D_DIM + t] + OMD * s) / denom;
    if (t == 0) cs_out[c] = cs;
}

// ---------------------------------------------------------------------------
// FALLBACK (R1-proven, only if ws too small): fp32 VALU GEMM + atomic epilogue.
__global__ __launch_bounds__(256) void vq_main_fb(
    const float* __restrict__ X, const float* __restrict__ E,
    const float* __restrict__ enorm,
    float* __restrict__ quant, float* __restrict__ indout,
    float* __restrict__ counts, float* __restrict__ esum) {
    constexpr int BN = 64, BC = 64, BK = 32, PADR = 68;
    __shared__ float As[BK * PADR];
    __shared__ float Bs[BK * PADR];
    __shared__ float redv[BN * 16];
    __shared__ int   redi[BN * 16];
    __shared__ int   rowsel[BN];

    const int tid = threadIdx.x;
    const int n0  = blockIdx.x * BN;
    const int tr  = tid >> 4;
    const int tc  = tid & 15;
    const int sr  = tid >> 2;
    const int sk  = tid & 3;

    const float4* X4 = reinterpret_cast<const float4*>(X);
    const float4* E4 = reinterpret_cast<const float4*>(E);

    float best[4];
    int   bidx[4];
#pragma unroll
    for (int i = 0; i < 4; i++) { best[i] = -3.4e38f; bidx[i] = 0; }

    for (int c0 = 0; c0 < C_CODES; c0 += BC) {
        float acc[4][4] = {};
        for (int k0 = 0; k0 < D_DIM; k0 += BK) {
            __syncthreads();
#pragma unroll
            for (int it = 0; it < 2; ++it) {
                int   k4 = sk + 4 * it;
                float4 av = X4[(n0 + sr) * 64 + (k0 >> 2) + k4];
                float4 bv = E4[(c0 + sr) * 64 + (k0 >> 2) + k4];
                int kk = k4 * 4;
                As[(kk + 0) * PADR + sr] = av.x;
                As[(kk + 1) * PADR + sr] = av.y;
                As[(kk + 2) * PADR + sr] = av.z;
                As[(kk + 3) * PADR + sr] = av.w;
                Bs[(kk + 0) * PADR + sr] = bv.x;
                Bs[(kk + 1) * PADR + sr] = bv.y;
                Bs[(kk + 2) * PADR + sr] = bv.z;
                Bs[(kk + 3) * PADR + sr] = bv.w;
            }
            __syncthreads();
#pragma unroll
            for (int k = 0; k < BK; ++k) {
                float4 a = *reinterpret_cast<const float4*>(&As[k * PADR + 4 * tr]);
                float4 b = *reinterpret_cast<const float4*>(&Bs[k * PADR + 4 * tc]);
                acc[0][0] += a.x * b.x; acc[0][1] += a.x * b.y;
                acc[0][2] += a.x * b.z; acc[0][3] += a.x * b.w;
                acc[1][0] += a.y * b.x; acc[1][1] += a.y * b.y;
                acc[1][2] += a.y * b.z; acc[1][3] += a.y * b.w;
                acc[2][0] += a.z * b.x; acc[2][1] += a.z * b.y;
                acc[2][2] += a.z * b.z; acc[2][3] += a.z * b.w;
                acc[3][0] += a.w * b.x; acc[3][1] += a.w * b.y;
                acc[3][2] += a.w * b.z; acc[3][3] += a.w * b.w;
            }
        }
        float4 en = *reinterpret_cast<const float4*>(&enorm[c0 + 4 * tc]);
        float enj[4] = {en.x, en.y, en.z, en.w};
#pragma unroll
        for (int i = 0; i < 4; i++)
#pragma unroll
            for (int j = 0; j < 4; j++) {
                float v = 2.0f * acc[i][j] - enj[j];
                int   c = c0 + 4 * tc + j;
                if (v > best[i]) { best[i] = v; bidx[i] = c; }
            }
    }

    __syncthreads();
#pragma unroll
    for (int i = 0; i < 4; i++) {
        redv[(4 * tr + i) * 16 + tc] = best[i];
        redi[(4 * tr + i) * 16 + tc] = bidx[i];
    }
    __syncthreads();
    if (tid < BN) {
        float bv = redv[tid * 16];
        int   bi = redi[tid * 16];
        for (int t = 1; t < 16; t++) {
            float v  = redv[tid * 16 + t];
            int   id = redi[tid * 16 + t];
            if (v > bv || (v == bv && id < bi)) { bv = v; bi = id; }
        }
        rowsel[tid] = bi;
        indout[n0 + tid] = (float)bi;
        unsafeAtomicAdd(&counts[bi], 1.0f);
    }
    __syncthreads();

    float4*   Q4   = reinterpret_cast<float4*>(quant);
    const int lane = tid & 63;
#pragma unroll
    for (int it = 0; it < 16; ++it) {
        int r   = (tid >> 6) + 4 * it;
        int idx = rowsel[r];
        float4 ev = E4[idx * 64 + lane];
        Q4[(n0 + r) * 64 + lane] = ev;
        float4 xv = X4[(n0 + r) * 64 + lane];
        float* dst = &esum[idx * D_DIM + lane * 4];
        unsafeAtomicAdd(dst + 0, xv.x);
        unsafeAtomicAdd(dst + 1, xv.y);
        unsafeAtomicAdd(dst + 2, xv.z);
        unsafeAtomicAdd(dst + 3, xv.w);
    }
}

__global__ __launch_bounds__(1024) void vq_fin1(const float* __restrict__ cs_in,
                                                const float* __restrict__ counts,
                                                float* __restrict__ cs_out,
                                                float* __restrict__ denom) {
    __shared__ float red[1024];
    int   c  = threadIdx.x;
    float cs = DECAY * cs_in[c] + OMD * counts[c];
    cs_out[c] = cs;
    red[c]    = cs;
    __syncthreads();
    for (int s = 512; s > 0; s >>= 1) {
        if (c < s) red[c] += red[c + s];
        __syncthreads();
    }
    float ntot = red[0];
    denom[c] = (cs + EPSV) / (ntot + (float)C_CODES * EPSV) * ntot;
}

__global__ __launch_bounds__(256) void vq_fin2(const float* __restrict__ ea,
                                               const float* __restrict__ esum,
                                               const float* __restrict__ denom,
                                               float* __restrict__ out) {
    int i = blockIdx.x * 256 + threadIdx.x;
    int c = i >> 6;
    float4 a = reinterpret_cast<const float4*>(ea)[i];
    float4 s = reinterpret_cast<const float4*>(esum)[i];
    float  d = denom[c];
    float4 o;
    o.x = (DECAY * a.x + OMD * s.x) / d;
    o.y = (DECAY * a.y + OMD * s.y) / d;
    o.z = (DECAY * a.z + OMD * s.z) / d;
    o.w = (DECAY * a.w + OMD * s.w) / d;
    reinterpret_cast<float4*>(out)[i] = o;
}

// ---------------------------------------------------------------------------
extern "C" void kernel_launch(void* const* d_in, const int* in_sizes, int n_in,
                              void* d_out, int out_size, void* d_ws, size_t ws_size,
                              hipStream_t stream) {
    const float* x            = (const float*)d_in[0];
    const float* embed        = (const float*)d_in[1];
    const float* embed_avg    = (const float*)d_in[2];
    const float* cluster_size = (const float*)d_in[3];

    float* out      = (float*)d_out;
    float* quant    = out;                                 // [N, D]
    float* ind      = out + (size_t)N_PTS * D_DIM;         // [N]
    float* emb_norm = ind + N_PTS;                         // [C, D]
    float* cs_out   = emb_norm + (size_t)C_CODES * D_DIM;  // [C]

    float* ws    = (float*)d_ws;
    float* enorm = ws + WS_ENORM;

    vq_enorm<<<C_CODES / 4, 256, 0, stream>>>(embed, enorm);

    if (ws_size >= WS_TOTAL_FLOATS * sizeof(float)) {
        float*    cssum = ws + WS_CSSUM;
        int*      pcnt  = (int*)(ws + WS_PCNT);
        float2*   cand  = (float2*)(ws + WS_CAND);
        float*    P     = ws + WS_CAND;                 // aliases cand (dead after merge3)
        _Float16* A16   = (_Float16*)(ws + WS_A16);
        _Float16* B16   = (_Float16*)(ws + WS_B16);

        vq_cssum<<<1, 1024, 0, stream>>>(cluster_size, cssum);
        vq_prep_x<<<N_PTS * 64 / 256, 256, 0, stream>>>(x, A16);
        vq_prep_e<<<C_CODES * 64 / 256, 256, 0, stream>>>(embed, B16);
        vq_gemm<<<dim3(C_CODES / 128, N_PTS / 128), 256, 0, stream>>>(A16, B16, enorm, cand);
        vq_merge3<<<N_PTS / 64, 256, 0, stream>>>(cand, embed, quant, ind);
        vq_part<<<dim3(C_CODES / PK, PG), 256, 0, stream>>>(x, ind, P, pcnt);
        vq_comb<<<C_CODES, 256, 0, stream>>>(P, pcnt, embed_avg, cluster_size, cssum,
                                             emb_norm, cs_out);
    } else {
        // fallback: R1-proven fp32 VALU path (~550 us)
        float* countsf = ws + WS_CAND;                  // [1024]
        float* esum    = ws + WS_CAND + 1024;           // [1024*256]
        float* denom   = ws + WS_A16;                   // [1024]
        hipMemsetAsync(countsf, 0, (1024 + (size_t)C_CODES * D_DIM) * sizeof(float), stream);
        vq_main_fb<<<N_PTS / 64, 256, 0, stream>>>(x, embed, enorm, quant, ind, countsf, esum);
        vq_fin1<<<1, 1024, 0, stream>>>(cluster_size, countsf, cs_out, denom);
        vq_fin2<<<(C_CODES * D_DIM / 4) / 256, 256, 0, stream>>>(embed_avg, esum, denom, emb_norm);
    }
}

// Round 10
// 218.094 us; speedup vs baseline: 2.5057x; 1.0514x over previous
//
#include <hip/hip_runtime.h>
#include <cstdint>

#define DECAY 0.99f
#define OMD   0.01f
#define EPSV  1e-5f

constexpr int N_PTS   = 32768;  // B*T
constexpr int D_DIM   = 256;
constexpr int C_CODES = 1024;
constexpr int KPACK   = 768;    // 3*D for the split GEMM

constexpr int PG = 4;           // ind chunks
constexpr int PK = 8;           // codes per partial block
constexpr int LCAP = 8192;      // worst-case list (chunk size), exact bound

typedef _Float16 half8  __attribute__((ext_vector_type(8)));
typedef _Float16 half4v __attribute__((ext_vector_type(4)));
typedef float    floatx4 __attribute__((ext_vector_type(4)));

// workspace layout (float offsets)
constexpr size_t WS_ENORM = 0;                        // float[1024]
constexpr size_t WS_CSSUM = 1024;                     // float[64]
constexpr size_t WS_PCNT  = 2048;                     // int[4*1024]
constexpr size_t WS_CAND  = 8192;                     // float2[32768*16]; later aliased by P[4][1024][256]
constexpr size_t WS_A16   = WS_CAND + 1048576;        // half[32768*768]
constexpr size_t WS_B16   = WS_A16 + 12582912;        // half[1024*768]
constexpr size_t WS_TOTAL_FLOATS = WS_B16 + 393216;

__device__ __forceinline__ void async_copy16(const void* g, void* s) {
    __builtin_amdgcn_global_load_lds(
        (const __attribute__((address_space(1))) unsigned int*)(uintptr_t)g,
        (__attribute__((address_space(3))) unsigned int*)(uintptr_t)s, 16, 0, 0);
}

// ---------------------------------------------------------------------------
// Split x (fp32) into [xh | xh | xl] fp16 rows of length 768.  (R3-proven)
__global__ __launch_bounds__(256) void vq_prep_x(const float* __restrict__ X,
                                                 _Float16* __restrict__ A) {
    int i = blockIdx.x * 256 + threadIdx.x;          // float4 index, N*D/4 total
    int n = i >> 6, kq = (i & 63) * 4;
    float4 v = reinterpret_cast<const float4*>(X)[i];
    _Float16 h0 = (_Float16)v.x, h1 = (_Float16)v.y, h2 = (_Float16)v.z, h3 = (_Float16)v.w;
    _Float16 l0 = (_Float16)(v.x - (float)h0), l1 = (_Float16)(v.y - (float)h1);
    _Float16 l2 = (_Float16)(v.z - (float)h2), l3 = (_Float16)(v.w - (float)h3);
    half4v hi = {h0, h1, h2, h3};
    half4v lo = {l0, l1, l2, l3};
    _Float16* row = A + (size_t)n * KPACK;
    *reinterpret_cast<half4v*>(row + kq)       = hi;
    *reinterpret_cast<half4v*>(row + 256 + kq) = hi;
    *reinterpret_cast<half4v*>(row + 512 + kq) = lo;
}

// Split e into [eh | el | eh] fp16 rows of length 768.  (R3-proven)
__global__ __launch_bounds__(256) void vq_prep_e(const float* __restrict__ E,
                                                 _Float16* __restrict__ B) {
    int i = blockIdx.x * 256 + threadIdx.x;          // float4 index, C*D/4 total
    int c = i >> 6, kq = (i & 63) * 4;
    float4 v = reinterpret_cast<const float4*>(E)[i];
    _Float16 h0 = (_Float16)v.x, h1 = (_Float16)v.y, h2 = (_Float16)v.z, h3 = (_Float16)v.w;
    _Float16 l0 = (_Float16)(v.x - (float)h0), l1 = (_Float16)(v.y - (float)h1);
    _Float16 l2 = (_Float16)(v.z - (float)h2), l3 = (_Float16)(v.w - (float)h3);
    half4v hi = {h0, h1, h2, h3};
    half4v lo = {l0, l1, l2, l3};
    _Float16* row = B + (size_t)c * KPACK;
    *reinterpret_cast<half4v*>(row + kq)       = hi;
    *reinterpret_cast<half4v*>(row + 256 + kq) = lo;
    *reinterpret_cast<half4v*>(row + 512 + kq) = hi;
}

// enorm[c] = sum_d embed[c,d]^2 (fp32-exact). One wave per code.  (R3-proven)
__global__ __launch_bounds__(256) void vq_enorm(const float* __restrict__ E,
                                                float* __restrict__ enorm) {
    int c    = blockIdx.x * 4 + (threadIdx.x >> 6);
    int lane = threadIdx.x & 63;
    float4 v = reinterpret_cast<const float4*>(E)[c * 64 + lane];
    float s  = v.x * v.x + v.y * v.y + v.z * v.z + v.w * v.w;
#pragma unroll
    for (int off = 32; off > 0; off >>= 1) s += __shfl_down(s, off, 64);
    if (lane == 0) enorm[c] = s;
}

// cs_sum = sum(cluster_size).  One block.
__global__ __launch_bounds__(1024) void vq_cssum(const float* __restrict__ cs_in,
                                                 float* __restrict__ out) {
    __shared__ float red[1024];
    int t = threadIdx.x;
    red[t] = cs_in[t];
    __syncthreads();
    for (int s = 512; s > 0; s >>= 1) {
        if (t < s) red[t] += red[t + s];
        __syncthreads();
    }
    if (t == 0) out[0] = red[0];
}

// ---------------------------------------------------------------------------
// MFMA GEMM: 128 rows x 128 codes per block, K=768 fp16, fused per-block
// row-argmax -> candidate (val, idx) per row.
// R10: 1-D grid + XCD-aware swizzle: all 8 code-tiles of a row-tile get the
// same (linear_id % 8) -> same XCD -> A-tile fetched into that L2 once.
__global__ __launch_bounds__(256, 2) void vq_gemm(
    const _Float16* __restrict__ A, const _Float16* __restrict__ B,
    const float* __restrict__ enorm, float2* __restrict__ cand) {
    __shared__ _Float16 As[128 * 64];   // [row][k], 16B chunks XOR-swizzled by row&7
    __shared__ _Float16 Bs[128 * 64];

    const int L      = blockIdx.x;          // 0..2047
    const int within = L >> 3;
    const int ct     = within & 7;          // code tile 0..7
    const int rt     = (L & 7) | ((within >> 3) << 3);  // row tile 0..255
    const int n0     = rt * 128;
    const int cb0    = ct * 128;

    const int tid = threadIdx.x;
    const int w   = tid >> 6;
    const int l   = tid & 63;

    const int srow = l >> 3;
    const int sq   = (l & 7) ^ srow;

    floatx4 acc[4][4] = {};

    for (int k0 = 0; k0 < KPACK; k0 += 64) {
        __syncthreads();
#pragma unroll
        for (int t = 0; t < 4; ++t) {
            int rr = w * 32 + t * 8;
            const _Float16* ga = A + (size_t)(n0 + rr + srow) * KPACK + k0 + sq * 8;
            async_copy16(ga, &As[rr * 64]);
            const _Float16* gb = B + (size_t)(cb0 + rr + srow) * KPACK + k0 + sq * 8;
            async_copy16(gb, &Bs[rr * 64]);
        }
        __syncthreads();
#pragma unroll
        for (int kk = 0; kk < 2; ++kk) {
            half8 af[4], bf[4];
            int qa = kk * 4 + (l >> 4);
#pragma unroll
            for (int i = 0; i < 4; ++i) {
                int row  = (w & 1) * 64 + 16 * i + (l & 15);
                af[i] = *reinterpret_cast<const half8*>(&As[row * 64 + (qa ^ (row & 7)) * 8]);
                int crow = (w >> 1) * 64 + 16 * i + (l & 15);
                bf[i] = *reinterpret_cast<const half8*>(&Bs[crow * 64 + (qa ^ (crow & 7)) * 8]);
            }
#pragma unroll
            for (int i = 0; i < 4; ++i)
#pragma unroll
                for (int j = 0; j < 4; ++j)
                    acc[i][j] = __builtin_amdgcn_mfma_f32_16x16x32_f16(af[i], bf[j], acc[i][j], 0, 0, 0);
        }
    }

    const int colbase = cb0 + (w >> 1) * 64 + (l & 15);
    float en[4];
#pragma unroll
    for (int j = 0; j < 4; ++j) en[j] = enorm[colbase + 16 * j];

#pragma unroll
    for (int i = 0; i < 4; ++i) {
#pragma unroll
        for (int reg = 0; reg < 4; ++reg) {
            float bv = -3.4e38f;
            int   bi = 0x7fffffff;
#pragma unroll
            for (int j = 0; j < 4; ++j) {
                float v = 2.0f * acc[i][j][reg] - en[j];
                int   c = colbase + 16 * j;
                if (v > bv || (v == bv && c < bi)) { bv = v; bi = c; }
            }
#pragma unroll
            for (int s = 1; s < 16; s <<= 1) {
                float ov = __shfl_xor(bv, s, 64);
                int   oi = __shfl_xor(bi, s, 64);
                if (ov > bv || (ov == bv && oi < bi)) { bv = ov; bi = oi; }
            }
            if ((l & 15) == 0) {
                int row = n0 + (w & 1) * 64 + 16 * i + (l >> 4) * 4 + reg;
                cand[(size_t)row * 16 + ct * 2 + (w >> 1)] = make_float2(bv, (float)bi);
            }
        }
    }
}

// ---------------------------------------------------------------------------
// Merge candidates -> index; gather quantize.  NO global atomics.  (R7-proven)
__global__ __launch_bounds__(256) void vq_merge3(
    const float2* __restrict__ cand, const float* __restrict__ E,
    float* __restrict__ quant, float* __restrict__ indout) {
    __shared__ int rowsel[64];
    const int tid = threadIdx.x;
    const int n0  = blockIdx.x * 64;

    if (tid < 64) {
        int r = n0 + tid;
        float bv = -3.4e38f;
        int   bi = 0x7fffffff;
#pragma unroll
        for (int t = 0; t < 16; ++t) {
            float2 cv = cand[(size_t)r * 16 + t];
            int ci = (int)cv.y;
            if (cv.x > bv || (cv.x == bv && ci < bi)) { bv = cv.x; bi = ci; }
        }
        bi &= (C_CODES - 1);                 // hard bound (defensive)
        rowsel[tid] = bi;
        indout[r]   = (float)bi;
    }
    __syncthreads();

    const float4* E4 = reinterpret_cast<const float4*>(E);
    float4*       Q4 = reinterpret_cast<float4*>(quant);
    const int lane = tid & 63;
#pragma unroll
    for (int it = 0; it < 16; ++it) {
        int r   = (tid >> 6) + 4 * it;
        int idx = rowsel[r];
        Q4[(n0 + r) * 64 + lane] = E4[idx * 64 + lane];
    }
}

// ---------------------------------------------------------------------------
// Partial esum: block (cg, g) scans ind chunk g for its PK=8 codes, gathers
// matching X rows with 8-deep ILP, writes P[g][code][d] + counts. (R9-proven)
__global__ __launch_bounds__(256) void vq_part(
    const float* __restrict__ X, const float* __restrict__ indf,
    float* __restrict__ P, int* __restrict__ pcnt) {
    __shared__ int list[LCAP];
    __shared__ int cnt[PK];
    __shared__ int lcnt;
    const int cg = blockIdx.x;   // 0..127 code group
    const int g  = blockIdx.y;   // 0..3 ind chunk
    const int t  = threadIdx.x;
    if (t == 0) lcnt = 0;
    if (t < PK) cnt[t] = 0;
    __syncthreads();

    const float4* I4 = reinterpret_cast<const float4*>(indf);
    float4 v[8];
#pragma unroll
    for (int j = 0; j < 8; ++j)            // 8 independent loads, one latency round
        v[j] = I4[g * 2048 + j * 256 + t];

#pragma unroll
    for (int j = 0; j < 8; ++j) {
        int base = (g * 2048 + j * 256 + t) * 4;
        int k0 = (int)v[j].x, k1 = (int)v[j].y, k2 = (int)v[j].z, k3 = (int)v[j].w;
        if ((k0 >> 3) == cg) { int p = atomicAdd(&lcnt, 1); atomicAdd(&cnt[k0 & 7], 1); if (p < LCAP) list[p] = ((base + 0) << 3) | (k0 & 7); }
        if ((k1 >> 3) == cg) { int p = atomicAdd(&lcnt, 1); atomicAdd(&cnt[k1 & 7], 1); if (p < LCAP) list[p] = ((base + 1) << 3) | (k1 & 7); }
        if ((k2 >> 3) == cg) { int p = atomicAdd(&lcnt, 1); atomicAdd(&cnt[k2 & 7], 1); if (p < LCAP) list[p] = ((base + 2) << 3) | (k2 & 7); }
        if ((k3 >> 3) == cg) { int p = atomicAdd(&lcnt, 1); atomicAdd(&cnt[k3 & 7], 1); if (p < LCAP) list[p] = ((base + 3) << 3) | (k3 & 7); }
    }
    __syncthreads();

    int m = lcnt; if (m > LCAP) m = LCAP;
    float acc[PK] = {0, 0, 0, 0, 0, 0, 0, 0};
    int r = 0;
    for (; r + 8 <= m; r += 8) {           // 8 coalesced row loads in flight
        int e[8];
        float val[8];
#pragma unroll
        for (int q = 0; q < 8; ++q) e[q] = list[r + q];
#pragma unroll
        for (int q = 0; q < 8; ++q) val[q] = X[(size_t)(e[q] >> 3) * D_DIM + t];
#pragma unroll
        for (int q = 0; q < 8; ++q) {
            int k = e[q] & 7;
#pragma unroll
            for (int kk = 0; kk < PK; ++kk) acc[kk] += (k == kk) ? val[q] : 0.0f;
        }
    }
    for (; r < m; ++r) {
        int e = list[r];
        float val = X[(size_t)(e >> 3) * D_DIM + t];
        int k = e & 7;
#pragma unroll
        for (int kk = 0; kk < PK; ++kk) acc[kk] += (k == kk) ? val : 0.0f;
    }

#pragma unroll
    for (int kk = 0; kk < PK; ++kk)
        P[((size_t)g * C_CODES + cg * PK + kk) * D_DIM + t] = acc[kk];
    if (t < PK) pcnt[g * C_CODES + cg * PK + t] = cnt[t];
}

// ---------------------------------------------------------------------------
// Combine partials + fused EMA/laplace epilogue.  One block per code. (R9-proven)
__global__ __launch_bounds__(256) void vq_comb(
    const float* __restrict__ P, const int* __restrict__ pcnt,
    const float* __restrict__ ea, const float* __restrict__ cs_in,
    const float* __restrict__ cs_sum,
    float* __restrict__ emb_norm, float* __restrict__ cs_out) {
    const int c = blockIdx.x;
    const int t = threadIdx.x;
    float s = 0.0f;
#pragma unroll
    for (int g = 0; g < PG; ++g)
        s += P[((size_t)g * C_CODES + c) * D_DIM + t];
    int total = pcnt[c] + pcnt[C_CODES + c] + pcnt[2 * C_CODES + c] + pcnt[3 * C_CODES + c];
    float cs    = DECAY * cs_in[c] + OMD * (float)total;
    float ntot  = DECAY * cs_sum[0] + OMD * (float)N_PTS;   // sum(cs_new) closed form
    float denom = (cs + EPSV) / (ntot + (float)C_CODES * EPSV) * ntot;
    emb_norm[(size_t)c * D_DIM + t] =
        (DECAY * ea[(size_t)c * D_DIM + t] + OMD * s) / denom;
    if (t == 0) cs_out[c] = cs;
}

// ---------------------------------------------------------------------------
// FALLBACK (R1-proven, only if ws too small): fp32 VALU GEMM + atomic epilogue.
__global__ __launch_bounds__(256) void vq_main_fb(
    const float* __restrict__ X, const float* __restrict__ E,
    const float* __restrict__ enorm,
    float* __restrict__ quant, float* __restrict__ indout,
    float* __restrict__ counts, float* __restrict__ esum) {
    constexpr int BN = 64, BC = 64, BK = 32, PADR = 68;
    __shared__ float As[BK * PADR];
    __shared__ float Bs[BK * PADR];
    __shared__ float redv[BN * 16];
    __shared__ int   redi[BN * 16];
    __shared__ int   rowsel[BN];

    const int tid = threadIdx.x;
    const int n0  = blockIdx.x * BN;
    const int tr  = tid >> 4;
    const int tc  = tid & 15;
    const int sr  = tid >> 2;
    const int sk  = tid & 3;

    const float4* X4 = reinterpret_cast<const float4*>(X);
    const float4* E4 = reinterpret_cast<const float4*>(E);

    float best[4];
    int   bidx[4];
#pragma unroll
    for (int i = 0; i < 4; i++) { best[i] = -3.4e38f; bidx[i] = 0; }

    for (int c0 = 0; c0 < C_CODES; c0 += BC) {
        float acc[4][4] = {};
        for (int k0 = 0; k0 < D_DIM; k0 += BK) {
            __syncthreads();
#pragma unroll
            for (int it = 0; it < 2; ++it) {
                int   k4 = sk + 4 * it;
                float4 av = X4[(n0 + sr) * 64 + (k0 >> 2) + k4];
                float4 bv = E4[(c0 + sr) * 64 + (k0 >> 2) + k4];
                int kk = k4 * 4;
                As[(kk + 0) * PADR + sr] = av.x;
                As[(kk + 1) * PADR + sr] = av.y;
                As[(kk + 2) * PADR + sr] = av.z;
                As[(kk + 3) * PADR + sr] = av.w;
                Bs[(kk + 0) * PADR + sr] = bv.x;
                Bs[(kk + 1) * PADR + sr] = bv.y;
                Bs[(kk + 2) * PADR + sr] = bv.z;
                Bs[(kk + 3) * PADR + sr] = bv.w;
            }
            __syncthreads();
#pragma unroll
            for (int k = 0; k < BK; ++k) {
                float4 a = *reinterpret_cast<const float4*>(&As[k * PADR + 4 * tr]);
                float4 b = *reinterpret_cast<const float4*>(&Bs[k * PADR + 4 * tc]);
                acc[0][0] += a.x * b.x; acc[0][1] += a.x * b.y;
                acc[0][2] += a.x * b.z; acc[0][3] += a.x * b.w;
                acc[1][0] += a.y * b.x; acc[1][1] += a.y * b.y;
                acc[1][2] += a.y * b.z; acc[1][3] += a.y * b.w;
                acc[2][0] += a.z * b.x; acc[2][1] += a.z * b.y;
                acc[2][2] += a.z * b.z; acc[2][3] += a.z * b.w;
                acc[3][0] += a.w * b.x; acc[3][1] += a.w * b.y;
                acc[3][2] += a.w * b.z; acc[3][3] += a.w * b.w;
            }
        }
        float4 en = *reinterpret_cast<const float4*>(&enorm[c0 + 4 * tc]);
        float enj[4] = {en.x, en.y, en.z, en.w};
#pragma unroll
        for (int i = 0; i < 4; i++)
#pragma unroll
            for (int j = 0; j < 4; j++) {
                float v = 2.0f * acc[i][j] - enj[j];
                int   c = c0 + 4 * tc + j;
                if (v > best[i]) { best[i] = v; bidx[i] = c; }
            }
    }

    __syncthreads();
#pragma unroll
    for (int i = 0; i < 4; i++) {
        redv[(4 * tr + i) * 16 + tc] = best[i];
        redi[(4 * tr + i) * 16 + tc] = bidx[i];
    }
    __syncthreads();
    if (tid < BN) {
        float bv = redv[tid * 16];
        int   bi = redi[tid * 16];
        for (int t = 1; t < 16; t++) {
            float v  = redv[tid * 16 + t];
            int   id = redi[tid * 16 + t];
            if (v > bv || (v == bv && id < bi)) { bv = v; bi = id; }
        }
        rowsel[tid] = bi;
        indout[n0 + tid] = (float)bi;
        unsafeAtomicAdd(&counts[bi], 1.0f);
    }
    __syncthreads();

    float4*   Q4   = reinterpret_cast<float4*>(quant);
    const int lane = tid & 63;
#pragma unroll
    for (int it = 0; it < 16; ++it) {
        int r   = (tid >> 6) + 4 * it;
        int idx = rowsel[r];
        float4 ev = E4[idx * 64 + lane];
        Q4[(n0 + r) * 64 + lane] = ev;
        float4 xv = X4[(n0 + r) * 64 + lane];
        float* dst = &esum[idx * D_DIM + lane * 4];
        unsafeAtomicAdd(dst + 0, xv.x);
        unsafeAtomicAdd(dst + 1, xv.y);
        unsafeAtomicAdd(dst + 2, xv.z);
        unsafeAtomicAdd(dst + 3, xv.w);
    }
}

__global__ __launch_bounds__(1024) void vq_fin1(const float* __restrict__ cs_in,
                                                const float* __restrict__ counts,
                                                float* __restrict__ cs_out,
                                                float* __restrict__ denom) {
    __shared__ float red[1024];
    int   c  = threadIdx.x;
    float cs = DECAY * cs_in[c] + OMD * counts[c];
    cs_out[c] = cs;
    red[c]    = cs;
    __syncthreads();
    for (int s = 512; s > 0; s >>= 1) {
        if (c < s) red[c] += red[c + s];
        __syncthreads();
    }
    float ntot = red[0];
    denom[c] = (cs + EPSV) / (ntot + (float)C_CODES * EPSV) * ntot;
}

__global__ __launch_bounds__(256) void vq_fin2(const float* __restrict__ ea,
                                               const float* __restrict__ esum,
                                               const float* __restrict__ denom,
                                               float* __restrict__ out) {
    int i = blockIdx.x * 256 + threadIdx.x;
    int c = i >> 6;
    float4 a = reinterpret_cast<const float4*>(ea)[i];
    float4 s = reinterpret_cast<const float4*>(esum)[i];
    float  d = denom[c];
    float4 o;
    o.x = (DECAY * a.x + OMD * s.x) / d;
    o.y = (DECAY * a.y + OMD * s.y) / d;
    o.z = (DECAY * a.z + OMD * s.z) / d;
    o.w = (DECAY * a.w + OMD * s.w) / d;
    reinterpret_cast<float4*>(out)[i] = o;
}

// ---------------------------------------------------------------------------
extern "C" void kernel_launch(void* const* d_in, const int* in_sizes, int n_in,
                              void* d_out, int out_size, void* d_ws, size_t ws_size,
                              hipStream_t stream) {
    const float* x            = (const float*)d_in[0];
    const float* embed        = (const float*)d_in[1];
    const float* embed_avg    = (const float*)d_in[2];
    const float* cluster_size = (const float*)d_in[3];

    float* out      = (float*)d_out;
    float* quant    = out;                                 // [N, D]
    float* ind      = out + (size_t)N_PTS * D_DIM;         // [N]
    float* emb_norm = ind + N_PTS;                         // [C, D]
    float* cs_out   = emb_norm + (size_t)C_CODES * D_DIM;  // [C]

    float* ws    = (float*)d_ws;
    float* enorm = ws + WS_ENORM;

    vq_enorm<<<C_CODES / 4, 256, 0, stream>>>(embed, enorm);

    if (ws_size >= WS_TOTAL_FLOATS * sizeof(float)) {
        float*    cssum = ws + WS_CSSUM;
        int*      pcnt  = (int*)(ws + WS_PCNT);
        float2*   cand  = (float2*)(ws + WS_CAND);
        float*    P     = ws + WS_CAND;                 // aliases cand (dead after merge3)
        _Float16* A16   = (_Float16*)(ws + WS_A16);
        _Float16* B16   = (_Float16*)(ws + WS_B16);

        vq_cssum<<<1, 1024, 0, stream>>>(cluster_size, cssum);
        vq_prep_x<<<N_PTS * 64 / 256, 256, 0, stream>>>(x, A16);
        vq_prep_e<<<C_CODES * 64 / 256, 256, 0, stream>>>(embed, B16);
        vq_gemm<<<2048, 256, 0, stream>>>(A16, B16, enorm, cand);
        vq_merge3<<<N_PTS / 64, 256, 0, stream>>>(cand, embed, quant, ind);
        vq_part<<<dim3(C_CODES / PK, PG), 256, 0, stream>>>(x, ind, P, pcnt);
        vq_comb<<<C_CODES, 256, 0, stream>>>(P, pcnt, embed_avg, cluster_size, cssum,
                                             emb_norm, cs_out);
    } else {
        // fallback: R1-proven fp32 VALU path (~550 us)
        float* countsf = ws + WS_CAND;                  // [1024]
        float* esum    = ws + WS_CAND + 1024;           // [1024*256]
        float* denom   = ws + WS_A16;                   // [1024]
        hipMemsetAsync(countsf, 0, (1024 + (size_t)C_CODES * D_DIM) * sizeof(float), stream);
        vq_main_fb<<<N_PTS / 64, 256, 0, stream>>>(x, embed, enorm, quant, ind, countsf, esum);
        vq_fin1<<<1, 1024, 0, stream>>>(cluster_size, countsf, cs_out, denom);
        vq_fin2<<<(C_CODES * D_DIM / 4) / 256, 256, 0, stream>>>(embed_avg, esum, denom, emb_norm);
    }
}